// Round 5
// baseline (380.285 us; speedup 1.0000x reference)
//
#include <hip/hip_runtime.h>
#include <stdint.h>

// Problem dims (fixed)
#define EMB 1024
#define HID 4096
#define NHEADS 16
#define DKH 64
#define SEQ 2048
#define BATCH 2
#define MROWS (BATCH * SEQ)  // 4096
#define GBK 64               // GEMM K-tile (128B LDS rows, 8x16B groups)

typedef unsigned short u16;
typedef unsigned int u32;
typedef __attribute__((ext_vector_type(8))) short short8;   // 8 bf16 (4 VGPRs)
typedef __attribute__((ext_vector_type(4))) float f32x4;    // MFMA 16x16 C/D
typedef __attribute__((ext_vector_type(16))) float f32x16;  // MFMA 32x32 C/D
typedef __attribute__((ext_vector_type(4))) u32 u32x4;
typedef __attribute__((ext_vector_type(2))) int i32x2;

// Softmax exp path: v_exp_f32 (=exp2) with log2e folded into Q weights.
#if __has_builtin(__builtin_amdgcn_exp2f)
#define QK_SCALE 0.18033688011f  // 0.125 * log2(e)
#define QK_CLAMP 43.3f           // 30 * log2(e)
__device__ __forceinline__ float pexp(float x) { return __builtin_amdgcn_exp2f(x); }
#else
#define QK_SCALE 0.125f
#define QK_CLAMP 30.0f
__device__ __forceinline__ float pexp(float x) { return __expf(x); }
#endif

__device__ __forceinline__ u16 f2bf(float f) {
    unsigned u = __float_as_uint(f);
    unsigned r = 0x7FFFu + ((u >> 16) & 1u);  // RNE
    return (u16)((u + r) >> 16);
}
__device__ __forceinline__ f32x4 mfma16(short8 a, short8 b, f32x4 c) {
    return __builtin_amdgcn_mfma_f32_16x16x32_bf16(a, b, c, 0, 0, 0);
}
__device__ __forceinline__ f32x16 mfma32(short8 a, short8 b, f32x16 c) {
    return __builtin_amdgcn_mfma_f32_32x32x16_bf16(a, b, c, 0, 0, 0);
}
// Async global->LDS, 16B/lane. LDS dest = wave-uniform base + lane*16.
__device__ __forceinline__ void gl_lds16(const u16* g, u16* l) {
    __builtin_amdgcn_global_load_lds(
        (__attribute__((address_space(1))) void*)g,
        (__attribute__((address_space(3))) void*)l, 16, 0, 0);
}
// lane l<32 keeps a, gets partner's b; lane l>=32 keeps b, gets partner's a.
__device__ __forceinline__ void plswap(u32& a, u32& b) {
#if __has_builtin(__builtin_amdgcn_permlane32_swap)
    i32x2 r = __builtin_amdgcn_permlane32_swap((int)a, (int)b, false, false);
    a = (u32)r.x; b = (u32)r.y;
#else
    const u32 ta = (u32)__shfl_xor((int)a, 32);
    const u32 tb = (u32)__shfl_xor((int)b, 32);
    const bool hi = (threadIdx.x & 32) != 0;
    const u32 na = hi ? tb : a;
    const u32 nb = hi ? b : ta;
    a = na; b = nb;
#endif
}
__device__ __forceinline__ short8 mk8(u32 a, u32 b, u32 c, u32 d) {
    u32x4 t; t.x = a; t.y = b; t.z = c; t.w = d;
    return __builtin_bit_cast(short8, t);
}

// ---------------------------------------------------------------------------
// Batched transpose + convert for the four 1024x1024 attention weights:
// z selects {wq,wk,wv,wo}; wq scaled by QK_SCALE (folds softmax scale into Q).
// Block (0,0,z=3) additionally reduces the mask to an "all ones" flag so the
// attention kernel can take a mask-free fast path (wave-uniform branch).
// ---------------------------------------------------------------------------
__global__ __launch_bounds__(256) void transpose_qkvo(
    const float* __restrict__ wq, const float* __restrict__ wk,
    const float* __restrict__ wv, const float* __restrict__ wo,
    u16* __restrict__ qkvT, u16* __restrict__ woT,
    const int* __restrict__ msk, int* __restrict__ flag) {
    __shared__ u16 t[32][33];
    const int z = blockIdx.z;
    const float* W = (z == 0) ? wq : (z == 1) ? wk : (z == 2) ? wv : wo;
    u16* WT = (z < 3) ? (qkvT + (size_t)z * EMB * EMB) : woT;
    const float scale = (z == 0) ? QK_SCALE : 1.0f;
    const int tx = threadIdx.x & 31, ty = threadIdx.x >> 5;
    const int k0 = blockIdx.y * 32, n0 = blockIdx.x * 32;
#pragma unroll
    for (int r = 0; r < 32; r += 8)
        t[ty + r][tx] = f2bf(scale * W[(size_t)(k0 + ty + r) * EMB + n0 + tx]);
    __syncthreads();
#pragma unroll
    for (int r = 0; r < 32; r += 8)
        WT[(size_t)(n0 + ty + r) * EMB + k0 + tx] = t[tx][ty + r];

    if (z == 3 && blockIdx.x == 0 && blockIdx.y == 0) {
        int v = 1;
        for (int i = threadIdx.x; i < BATCH * SEQ; i += 256)
            v &= (msk[i] != 0) ? 1 : 0;
        v = __all(v) ? 1 : 0;
        __shared__ int rr[4];
        if ((threadIdx.x & 63) == 0) rr[threadIdx.x >> 6] = v;
        __syncthreads();
        if (threadIdx.x == 0) flag[0] = rr[0] & rr[1] & rr[2] & rr[3];
    }
}

// ---------------------------------------------------------------------------
// Transpose + convert: W fp32 [K][N] -> WT bf16 [N][K]. 32x32 LDS tiles.
// ---------------------------------------------------------------------------
__global__ __launch_bounds__(256) void transpose_bf16(
    const float* __restrict__ W, u16* __restrict__ WT, int K, int N) {
    __shared__ u16 t[32][33];
    const int tx = threadIdx.x & 31, ty = threadIdx.x >> 5;  // ty 0..7
    const int k0 = blockIdx.y * 32, n0 = blockIdx.x * 32;
#pragma unroll
    for (int r = 0; r < 32; r += 8)
        t[ty + r][tx] = f2bf(W[(size_t)(k0 + ty + r) * N + n0 + tx]);
    __syncthreads();
#pragma unroll
    for (int r = 0; r < 32; r += 8)
        WT[(size_t)(n0 + ty + r) * K + k0 + tx] = t[tx][ty + r];
}

// ---------------------------------------------------------------------------
// LayerNorm: one block per row of 1024, fp32 in, bf16 out. Bessel var,
// denom (std+eps), scalar alpha/beta.
// ---------------------------------------------------------------------------
__global__ __launch_bounds__(256) void ln_kernel(
    const float* __restrict__ x, u16* __restrict__ out,
    const float* __restrict__ alpha_p, const float* __restrict__ beta_p) {
    const int row = blockIdx.x;
    const int tid = threadIdx.x;
    float4 v = reinterpret_cast<const float4*>(x + (size_t)row * EMB)[tid];

    __shared__ float red[4];
    float s = v.x + v.y + v.z + v.w;
    for (int off = 32; off; off >>= 1) s += __shfl_down(s, off);
    if ((tid & 63) == 0) red[tid >> 6] = s;
    __syncthreads();
    float mean = (red[0] + red[1] + red[2] + red[3]) * (1.0f / EMB);
    __syncthreads();

    float d0 = v.x - mean, d1 = v.y - mean, d2 = v.z - mean, d3 = v.w - mean;
    float sq = d0 * d0 + d1 * d1 + d2 * d2 + d3 * d3;
    for (int off = 32; off; off >>= 1) sq += __shfl_down(sq, off);
    if ((tid & 63) == 0) red[tid >> 6] = sq;
    __syncthreads();
    float var = (red[0] + red[1] + red[2] + red[3]) * (1.0f / (EMB - 1));
    float inv = 1.0f / (sqrtf(var) + 1e-6f);
    float a = alpha_p[0], b = beta_p[0];

    ushort4 o;
    o.x = f2bf(a * d0 * inv + b);
    o.y = f2bf(a * d1 * inv + b);
    o.z = f2bf(a * d2 * inv + b);
    o.w = f2bf(a * d3 * inv + b);
    reinterpret_cast<ushort4*>(out + (size_t)row * EMB)[tid] = o;
}

// ---------------------------------------------------------------------------
// MFMA GEMM, 512 threads (8 waves). C[M,N] = A[M,K] @ B[K,N], B transposed
// bf16 (BT [N][K]). 128 x BN tile. LDS rows 128B = 8x16B groups, group g at
// slot g^(row&7) (swizzle folded into the global source address) -> frag
// ds_read_b128 2-way = free.
//
// Pipeline (NBUF):
//  - BN==128: 2-buffer, one __syncthreads()/K-step. 64 KB LDS.
//  - BN==64: 3-buffer, COUNTED vmcnt (2 tiles in flight, never drained).
//    72 KB LDS, 2 blocks/CU.
//
// XCD remap: bid&7 = XCD; requires gridDim.y % 8 == 0 (here ny=32).
// out_mode: 0 bf16 [M][N] | 1 fp32 [M][N] (+res may alias C) |
//           2 bf16 transposed [N][M] | 3 fused QKV (C=Q, Kb_out=K, VT_out=V^T).
// ---------------------------------------------------------------------------
template <int BN, int NWM>
__global__ __launch_bounds__(512) void gemm_mfma(
    const u16* __restrict__ A, const u16* __restrict__ BT, void* C,
    const float* __restrict__ bias, const void* res,
    int M, int N, int K, int relu, int out_mode,
    u16* __restrict__ Kb_out, u16* __restrict__ VT_out) {
    constexpr int NWN = 8 / NWM;
    constexpr int WM = 128 / (16 * NWM);
    constexpr int WN = BN / (16 * NWN);
    constexpr int NBUF = (BN == 64) ? 3 : 2;
    __shared__ u16 As[NBUF][128][GBK];   // NBUF x 16 KB
    __shared__ u16 Bs[NBUF][BN][GBK];    // NBUF x (8|16) KB

    const int tid = threadIdx.x;
    const int wave = tid >> 6, lane = tid & 63;
    const int quad = lane >> 4, lc = lane & 15;
    const int wm = wave % NWM, wn = wave / NWM;

    // XCD-aware remap (speed-only heuristic)
    const int nx = gridDim.x;
    const int bid = blockIdx.y * nx + blockIdx.x;
    const int xcd = bid & 7, sl = bid >> 3;
    const int nyx = gridDim.y >> 3;
    const int bcol = sl % nx;
    const int brow = (sl / nx) + xcd * nyx;
    const int row0 = brow * 128, col0 = bcol * BN;

    // Staging lane map: 8 rows per instr; swizzled global group.
    const int srow = lane >> 3;            // 0..7
    const int scg = (lane & 7) ^ srow;     // global 16B-group for this lane

    f32x4 acc[WM][WN] = {};

    auto stage = [&](int k0, int buf) {
#pragma unroll
        for (int i = 0; i < 2; ++i) {      // A: 128 rows, 8 waves x 2 instrs
            const int rb = wave * 16 + i * 8;
            gl_lds16(A + (size_t)(row0 + rb + srow) * K + k0 + scg * 8,
                     &As[buf][rb][0]);
        }
        if constexpr (BN == 128) {
#pragma unroll
            for (int i = 0; i < 2; ++i) {
                const int rb = wave * 16 + i * 8;
                gl_lds16(BT + (size_t)(col0 + rb + srow) * K + k0 + scg * 8,
                         &Bs[buf][rb][0]);
            }
        } else {                            // BN == 64: 1 instr/wave
            const int rb = wave * 8;
            gl_lds16(BT + (size_t)(col0 + rb + srow) * K + k0 + scg * 8,
                     &Bs[buf][rb][0]);
        }
    };

    auto compute = [&](int cur) {
#pragma unroll
        for (int s = 0; s < 2; ++s) {      // two K=32 substeps per BK=64
            short8 af[WM], bfv[WN];
#pragma unroll
            for (int i = 0; i < WM; ++i) {
                const int ar = wm * (16 * WM) + i * 16 + lc;
                af[i] = *reinterpret_cast<const short8*>(
                    &As[cur][ar][(((s * 4 + quad) ^ (ar & 7))) * 8]);
            }
#pragma unroll
            for (int j = 0; j < WN; ++j) {
                const int br = wn * (16 * WN) + j * 16 + lc;
                bfv[j] = *reinterpret_cast<const short8*>(
                    &Bs[cur][br][(((s * 4 + quad) ^ (br & 7))) * 8]);
            }
#pragma unroll
            for (int i = 0; i < WM; ++i)
#pragma unroll
                for (int j = 0; j < WN; ++j)
                    acc[i][j] = mfma16(af[i], bfv[j], acc[i][j]);
        }
    };

    if constexpr (NBUF == 2) {
        stage(0, 0);
        __syncthreads();                    // drain -> chunk 0 resident
        int cur = 0;
        for (int k0 = 0; k0 < K; k0 += GBK) {
            if (k0 + GBK < K) stage(k0 + GBK, cur ^ 1);  // prefetch, no wait
            compute(cur);
            __syncthreads();   // publishes prefetched chunk; ends reads of cur
            cur ^= 1;
        }
    } else {
        // 3-buffer counted-vmcnt pipeline (2 tiles always in flight).
        stage(0, 0);
        if (GBK < K) stage(GBK, 1);
        int cur = 0;
        for (int k0 = 0; k0 < K; k0 += GBK) {
            if (k0 + 2 * GBK < K) {
                int nb = cur + 2; if (nb >= 3) nb -= 3;
                stage(k0 + 2 * GBK, nb);    // overwrites buffer whose reads
            }                               // ended at last iter's barrier(b)
            const int rem = (K - k0) >> 6;  // tiles remaining incl. current
            if (rem > 2)       asm volatile("s_waitcnt vmcnt(6)" ::: "memory");
            else if (rem == 2) asm volatile("s_waitcnt vmcnt(3)" ::: "memory");
            else               asm volatile("s_waitcnt vmcnt(0)" ::: "memory");
            __builtin_amdgcn_s_barrier();           // (a) tile cur resident
            __builtin_amdgcn_sched_barrier(0);      // rule #18 fence
            compute(cur);
            __builtin_amdgcn_s_barrier();           // (b) reads of cur done
            cur = (cur == 2) ? 0 : cur + 1;
        }
    }

    // Resolve output target (mode 3: segment-uniform per block since BN<=1024).
    u16* Cb = (u16*)C;
    int mode = out_mode, ncols = N, lcol0 = col0;
    if (out_mode == 3) {
        const int seg = col0 >> 10;
        lcol0 = col0 & 1023;
        ncols = EMB;
        if (seg == 1) { Cb = Kb_out; mode = 0; }
        else if (seg == 2) { Cb = VT_out; mode = 2; }
        else { mode = 0; }
    }

    // Epilogue. C/D layout: col = lc, row = quad*4 + r.
#pragma unroll
    for (int j = 0; j < WN; ++j) {
        const int col = lcol0 + wn * (16 * WN) + j * 16 + lc;
        const float bv = bias ? bias[col] : 0.f;
#pragma unroll
        for (int i = 0; i < WM; ++i) {
            const int rbase = row0 + wm * (16 * WM) + i * 16 + quad * 4;
            if (mode == 2) {  // bf16 transposed [N][M]
                ushort4 o;
                o.x = f2bf(acc[i][j][0]); o.y = f2bf(acc[i][j][1]);
                o.z = f2bf(acc[i][j][2]); o.w = f2bf(acc[i][j][3]);
                *reinterpret_cast<ushort4*>(Cb + (size_t)col * M + rbase) = o;
            } else {
#pragma unroll
                for (int r = 0; r < 4; ++r) {
                    const size_t idx = (size_t)(rbase + r) * ncols + col;
                    float v = acc[i][j][r] + bv;
                    if (relu) v = fmaxf(v, 0.f);
                    if (res) v += ((const float*)res)[idx];
                    if (mode == 1) ((float*)C)[idx] = v;
                    else Cb[idx] = f2bf(v);
                }
            }
        }
    }
}

// ---------------------------------------------------------------------------
// Wide-tile MFMA GEMM for the LDS-bandwidth-bound FFN shapes: 256 threads =
// 4 waves, 128x128 block tile, each wave owns a 64x64 output (2x2 grid of
// 32x32x16 MFMA tiles). Per BK=64 K-step a wave does 16 ds_read_b128 and
// 16 mfma32 -> 32768 FLOP per 1KB LDS read, 2x the 16x16 kernels' ratio.
// LDS:MFMA cycle ratio ~1.5 (vs ~2.7 in the BN=64 16x16 config) -> MfmaUtil
// cap ~67%. 2-buffer + COUNTED vmcnt(8) (one 8-load tile always in flight,
// never drained; raw barriers; rule-#18 sched fence). 64 KB LDS.
// Fragment layouts reused from the verified attention kernel:
//   A-frag: lane holds A[m = l&31][k = (l>>5)*8 + j]   (Ks/ka pattern)
//   B-frag: lane holds B[k = (l>>5)*8 + j][n = l&31]   (qb pattern, BT rows)
//   C/D   : col = l&31, row = (r&3) + 8*(r>>2) + 4*(l>>5)
// out: fp32out ? fp32 [M][N] (+res may alias C) : bf16 [M][N]; bias; relu.
// XCD remap as in gemm_mfma (gridDim.y % 8 == 0).
// ---------------------------------------------------------------------------
__global__ __launch_bounds__(256) void gemm_w64(
    const u16* __restrict__ A, const u16* __restrict__ BT, void* C,
    const float* __restrict__ bias, const void* res,
    int M, int N, int K, int relu, int fp32out) {
    __shared__ u16 As[2][128][GBK];   // 2 x 16 KB
    __shared__ u16 Bs[2][128][GBK];   // 2 x 16 KB

    const int tid = threadIdx.x;
    const int wave = tid >> 6, lane = tid & 63;
    const int hi = lane >> 5, ln31 = lane & 31;
    const int wm = wave >> 1, wn = wave & 1;   // 2x2 wave grid, 64x64 each

    // XCD-aware remap
    const int nx = gridDim.x;
    const int bid = blockIdx.y * nx + blockIdx.x;
    const int xcd = bid & 7, sl = bid >> 3;
    const int nyx = gridDim.y >> 3;
    const int bcol = sl % nx;
    const int brow = (sl / nx) + xcd * nyx;
    const int row0 = brow * 128, col0 = bcol * 128;

    // Staging lane map: 8 rows/instr; swizzled global 16B-group.
    const int srow = lane >> 3;            // 0..7
    const int scg = (lane & 7) ^ srow;     // global group for this lane

    f32x16 a00 = {}, a01 = {}, a10 = {}, a11 = {};

    auto stage = [&](int k0, int buf) {
#pragma unroll
        for (int i = 0; i < 4; ++i) {      // A: 128 rows, 4 waves x 4 instrs
            const int rb = wave * 32 + i * 8;
            gl_lds16(A + (size_t)(row0 + rb + srow) * K + k0 + scg * 8,
                     &As[buf][rb][0]);
        }
#pragma unroll
        for (int i = 0; i < 4; ++i) {      // B: 128 cols (BT rows)
            const int rb = wave * 32 + i * 8;
            gl_lds16(BT + (size_t)(col0 + rb + srow) * K + k0 + scg * 8,
                     &Bs[buf][rb][0]);
        }
    };

    const int nt = K >> 6;                 // BK=64 tiles
    stage(0, 0);
    int cur = 0;
    for (int t = 0; t < nt; ++t) {
        if (t + 1 < nt) {
            stage((t + 1) << 6, cur ^ 1);  // prefetch (prev reads of cur^1
                                            // ended at last trailing barrier)
            asm volatile("s_waitcnt vmcnt(8)" ::: "memory");  // tile t landed
        } else {
            asm volatile("s_waitcnt vmcnt(0)" ::: "memory");
        }
        __builtin_amdgcn_s_barrier();           // (a) tile t resident (all waves)
        __builtin_amdgcn_sched_barrier(0);      // rule #18 fence

#pragma unroll
        for (int s = 0; s < 4; ++s) {      // four K=16 substeps per BK=64
            const int slb = ((2 * s + hi) ^ (ln31 & 7)) * 8;
            const short8 fa0 = *reinterpret_cast<const short8*>(
                &As[cur][wm * 64 + ln31][slb]);
            const short8 fa1 = *reinterpret_cast<const short8*>(
                &As[cur][wm * 64 + 32 + ln31][slb]);
            const short8 fb0 = *reinterpret_cast<const short8*>(
                &Bs[cur][wn * 64 + ln31][slb]);
            const short8 fb1 = *reinterpret_cast<const short8*>(
                &Bs[cur][wn * 64 + 32 + ln31][slb]);
            a00 = mfma32(fa0, fb0, a00);
            a01 = mfma32(fa0, fb1, a01);
            a10 = mfma32(fa1, fb0, a10);
            a11 = mfma32(fa1, fb1, a11);
        }
        __builtin_amdgcn_s_barrier();           // (b) reads of cur done
        cur ^= 1;
    }

    // Epilogue: 2x2 32x32 tiles. row = (r&3)+8*(r>>2)+4*hi, col = ln31.
#pragma unroll
    for (int ti = 0; ti < 2; ++ti)
#pragma unroll
        for (int tj = 0; tj < 2; ++tj) {
            const f32x16& av = (ti == 0) ? (tj == 0 ? a00 : a01)
                                         : (tj == 0 ? a10 : a11);
            const int col = col0 + wn * 64 + tj * 32 + ln31;
            const float bv = bias ? bias[col] : 0.f;
            const int rb2 = row0 + wm * 64 + ti * 32 + 4 * hi;
#pragma unroll
            for (int r = 0; r < 16; ++r) {
                const int row = rb2 + (r & 3) + 8 * (r >> 2);
                const size_t idx = (size_t)row * N + col;
                float v = av[r] + bv;
                if (relu) v = fmaxf(v, 0.f);
                if (res) v += ((const float*)res)[idx];
                if (fp32out) ((float*)C)[idx] = v;
                else ((u16*)C)[idx] = f2bf(v);
            }
        }
}

// ---------------------------------------------------------------------------
// MFMA flash attention v4: 32x32x16 MFMA, 512 threads = 8 waves =
// 4 query-tiles (32 q each) x 2 key-streams (split-K over the sequence).
// Chunk of 128 keys staged per iteration (double-buffered); stream s owns
// keys [s*64, s*64+64) of each chunk. Transposed scores St = K·Q^T: lane
// holds query lane&31 across all its score regs, so P needs only a
// lane<->lane+32 exchange: truncating v_perm bf16 pack + permlane32_swap
// (no LDS P round-trip at all). No online max (Q carries QK_SCALE incl.
// log2e; exp2; clamp). Mask fast path via precomputed all-ones flag.
// Streams merge O and softmax denominators through LDS at the end (legal
// because exp is absolute, not max-shifted). Grid: 512 blocks,
// bid&31 = b*16+h (XCD affinity per head), bid>>5 = 128-query block.
// ---------------------------------------------------------------------------
__global__ __launch_bounds__(512, 4) void attn_mfma(
    const u16* __restrict__ Q, const u16* __restrict__ K,
    const u16* __restrict__ VT, const int* __restrict__ mask,
    const int* __restrict__ mflag, u16* __restrict__ O) {
    const int tid = threadIdx.x;
    const int wave = tid >> 6, lane = tid & 63;
    const int hi = lane >> 5, ln31 = lane & 31;
    const int qt = wave >> 1, s = wave & 1;
    const int H = blockIdx.x & 31;         // b*16+h
    const int qblk = blockIdx.x >> 5;      // 0..15
    const int h = H & 15, b = H >> 4;

    // LDS arena (64 KB): main loop uses Ks+Vs; epilogue aliases Om+Ls.
    __shared__ __align__(16) char smem[65536];
    u16 (*Ks)[128][DKH] = (u16(*)[128][DKH])smem;          // [2][128][64]
    u16 (*Vs)[DKH][128] = (u16(*)[DKH][128])(smem + 32768);  // [2][64][128]

    const int fast = mflag[0];

    // Q as B-operand frags: B[k = f*16 + hi*8 + j][n = q = ln31]
    const u16* qp = Q + (size_t)(b * SEQ + qblk * 128 + qt * 32 + ln31) * EMB
                      + h * DKH + hi * 8;
    short8 qb[4];
#pragma unroll
    for (int f = 0; f < 4; ++f)
        qb[f] = *reinterpret_cast<const short8*>(qp + f * 16);

    // Staging lane maps (swizzle folded into GLOBAL source; LDS dest linear).
    const int srow = lane >> 3, scg = (lane & 7) ^ srow;   // K: 8 tok/instr
    const int svr = lane >> 4, ssl = lane & 15;            // V: 4 dim/instr

    auto stage = [&](int kc, int buf) {
#pragma unroll
        for (int i = 0; i < 2; ++i) {      // K: 128 tokens, 8 waves x 2
            const int t8 = wave * 16 + i * 8;
            gl_lds16(K + (size_t)(b * SEQ + kc + t8 + srow) * EMB + h * DKH + scg * 8,
                     &Ks[buf][t8][0]);
        }
#pragma unroll
        for (int i = 0; i < 2; ++i) {      // V^T: 64 dims, 8 waves x 2
            const int d4 = wave * 8 + i * 4;
            const int dim = d4 + svr;
            const int gv = ssl ^ (dim & 15);
            gl_lds16(VT + (size_t)(h * DKH + dim) * MROWS + b * SEQ + kc + gv * 8,
                     &Vs[buf][d4][0]);
        }
    };

    f32x16 o0 = {}, o1 = {};   // O[q=row][dim], n-tiles dim 0-31 / 32-63
    float rs = 0.f;            // partial denom for query ln31 (this stream)
    const int tok0 = s * 64;   // this wave's key base within the 128-chunk

    stage(0, 0);
    __syncthreads();
    int cur = 0;

    for (int kc = 0; kc < SEQ; kc += 128) {
        if (kc + 128 < SEQ) stage(kc + 128, cur ^ 1);  // prefetch, no wait

#pragma unroll
        for (int mt = 0; mt < 2; ++mt) {   // two 32-key m-tiles
            const int trow = tok0 + mt * 32 + ln31;
            f32x16 st = {};
#pragma unroll
            for (int f = 0; f < 4; ++f) {  // K-dim 64 = 4 steps of 16
                const int slot = (2 * f + hi) ^ (trow & 7);
                const short8 ka = *reinterpret_cast<const short8*>(
                    &Ks[cur][trow][slot * 8]);
                st = mfma32(ka, qb[f], st);
            }
            // st[r]: score(key = mt*32 + (r&3)+8*(r>>2)+4*hi, query = ln31)
            if (fast) {
#pragma unroll
                for (int r = 0; r < 16; ++r)
                    st[r] = pexp(fminf(st[r], QK_CLAMP));
            } else {
#pragma unroll
                for (int g = 0; g < 4; ++g) {
                    const int4 mk = *reinterpret_cast<const int4*>(
                        mask + b * SEQ + kc + tok0 + mt * 32 + g * 8 + hi * 4);
                    const int* mkp = &mk.x;
#pragma unroll
                    for (int r4 = 0; r4 < 4; ++r4) {
                        const int r = g * 4 + r4;
                        const float pv = pexp(fminf(st[r], QK_CLAMP));
                        st[r] = mkp[r4] ? pv : 0.f;
                    }
                }
            }
            rs += (((st[0] + st[1]) + (st[2] + st[3])) +
                   ((st[4] + st[5]) + (st[6] + st[7]))) +
                  (((st[8] + st[9]) + (st[10] + st[11])) +
                   ((st[12] + st[13]) + (st[14] + st[15])));

            // Truncating bf16 pack of adjacent-key pairs, then lane<->lane+32
            // swaps build the PV A-frags (A[m=q=ln31][k=hi*8+j]) in-register.
            u32 pk0 = __builtin_amdgcn_perm(__float_as_uint(st[1]),
                                            __float_as_uint(st[0]), 0x07060302u);
            u32 pk1 = __builtin_amdgcn_perm(__float_as_uint(st[3]),
                                            __float_as_uint(st[2]), 0x07060302u);
            u32 pk2 = __builtin_amdgcn_perm(__float_as_uint(st[5]),
                                            __float_as_uint(st[4]), 0x07060302u);
            u32 pk3 = __builtin_amdgcn_perm(__float_as_uint(st[7]),
                                            __float_as_uint(st[6]), 0x07060302u);
            u32 pk4 = __builtin_amdgcn_perm(__float_as_uint(st[9]),
                                            __float_as_uint(st[8]), 0x07060302u);
            u32 pk5 = __builtin_amdgcn_perm(__float_as_uint(st[11]),
                                            __float_as_uint(st[10]), 0x07060302u);
            u32 pk6 = __builtin_amdgcn_perm(__float_as_uint(st[13]),
                                            __float_as_uint(st[12]), 0x07060302u);
            u32 pk7 = __builtin_amdgcn_perm(__float_as_uint(st[15]),
                                            __float_as_uint(st[14]), 0x07060302u);
            plswap(pk0, pk2);   // pk0: lo keys(0,1)/hi(8,9); pk2: lo(4,5)/hi(12,13)
            plswap(pk1, pk3);
            plswap(pk4, pk6);
            plswap(pk5, pk7);
            const short8 fr0 = mk8(pk0, pk1, pk2, pk3);  // keys mt*32 +  0..15
            const short8 fr1 = mk8(pk4, pk5, pk6, pk7);  // keys mt*32 + 16..31

#pragma unroll
            for (int sub = 0; sub < 2; ++sub) {
                const short8 fr = sub ? fr1 : fr0;
                const int g = s * 8 + (2 * mt + sub) * 2 + hi;  // token 16B-group
#pragma unroll
                for (int nt = 0; nt < 2; ++nt) {
                    const int drow = nt * 32 + ln31;
                    const short8 vb = *reinterpret_cast<const short8*>(
                        &Vs[cur][drow][(g ^ (drow & 15)) * 8]);
                    if (nt == 0) o0 = mfma32(fr, vb, o0);
                    else         o1 = mfma32(fr, vb, o1);
                }
            }
        }
        __syncthreads();   // publishes prefetched chunk; ends reads of cur
        cur ^= 1;
    }

    // ---- merge the two key-streams of each query-tile via LDS ----
    rs += __shfl_xor(rs, 32);               // full stream-partial for query ln31

    float* Om = (float*)smem;               // [4][32][68] fp32 (padded rows)
    float* Ls = (float*)(smem + 34816);     // [128]

    if (s == 0) {
#pragma unroll
        for (int nt = 0; nt < 2; ++nt)
#pragma unroll
            for (int r = 0; r < 16; ++r) {
                const int row = (r & 3) + 8 * (r >> 2) + 4 * hi;
                Om[(qt * 32 + row) * 68 + nt * 32 + ln31] = nt ? o1[r] : o0[r];
            }
        if (lane < 32) Ls[qt * 32 + ln31] = rs;
    }
    __syncthreads();
    if (s == 1) {
        const float lt = rs + Ls[qt * 32 + ln31];
        if (lane < 32) Ls[qt * 32 + ln31] = lt;
#pragma unroll
        for (int nt = 0; nt < 2; ++nt)
#pragma unroll
            for (int r = 0; r < 16; ++r) {
                const int row = (r & 3) + 8 * (r >> 2) + 4 * hi;
                const int idx = (qt * 32 + row) * 68 + nt * 32 + ln31;
                Om[idx] += nt ? o1[r] : o0[r];
            }
    }
    __syncthreads();

    // ---- coalesced vectorized writeback: thread -> (q = tid>>2, seg) ----
    {
        const int q = tid >> 2, seg = tid & 3;
        const float inv = 1.0f / Ls[q];
        const float* src = Om + q * 68 + seg * 16;
        u16* dst = O + (size_t)(b * SEQ + qblk * 128 + q) * EMB + h * DKH + seg * 16;
#pragma unroll
        for (int i = 0; i < 4; ++i) {
            const float4 v = *reinterpret_cast<const float4*>(src + i * 4);
            ushort4 ou;
            ou.x = f2bf(v.x * inv); ou.y = f2bf(v.y * inv);
            ou.z = f2bf(v.z * inv); ou.w = f2bf(v.w * inv);
            *reinterpret_cast<ushort4*>(dst + i * 4) = ou;
        }
    }
}

// ---------------------------------------------------------------------------
// Orchestration. fp32 I/O, bf16 internals. ws (48 MB):
//   [0,8M)    act: xn -> attn_out -> xn2
//   [8,16M)   Q   --+
//   [16,24M)  K     +-- overlaid by f1 [8,40M) after attention
//   [24,32M)  VT  --+
//   [32M)     mask all-ones flag (int; dead once f1 is written)
//   [40,46M)  wqkvT [3072][1024]; [46,48M) woT --> later ffT [40,48M)
// h (fp32) lives in d_out (in-place residual in final GEMM).
// ---------------------------------------------------------------------------
extern "C" void kernel_launch(void* const* d_in, const int* in_sizes, int n_in,
                              void* d_out, int out_size, void* d_ws, size_t ws_size,
                              hipStream_t stream) {
    const float* x     = (const float*)d_in[0];
    const int*   mask  = (const int*)d_in[1];
    const float* wq    = (const float*)d_in[2];
    const float* wk    = (const float*)d_in[3];
    const float* wv    = (const float*)d_in[4];
    const float* wo    = (const float*)d_in[5];
    const float* ff1_w = (const float*)d_in[6];
    const float* ff1_b = (const float*)d_in[7];
    const float* ff2_w = (const float*)d_in[8];
    const float* ff2_b = (const float*)d_in[9];
    const float* ln1_a = (const float*)d_in[10];
    const float* ln1_b = (const float*)d_in[11];
    const float* ln2_a = (const float*)d_in[12];
    const float* ln2_b = (const float*)d_in[13];
    float* out = (float*)d_out;

    char* ws = (char*)d_ws;
    const size_t MB = 1u << 20;
    u16* act   = (u16*)(ws + 0);
    u16* Qb    = (u16*)(ws + 8 * MB);
    u16* Kb    = (u16*)(ws + 16 * MB);
    u16* VTb   = (u16*)(ws + 24 * MB);
    int* mflag = (int*)(ws + 32 * MB);   // free until f1 is written (step 6)
    u16* f1    = (u16*)(ws + 8 * MB);    // 32 MB, overlays Q/K/VT (dead)
    u16* wqkvT = (u16*)(ws + 40 * MB);   // [3*EMB][EMB] bf16 = 6 MB
    u16* woT   = (u16*)(ws + 46 * MB);   // 2 MB
    u16* ffT   = (u16*)(ws + 40 * MB);   // 8 MB rotating (ff1T, then ff2T)

    // 0) batched weight transposes (wq scaled by QK_SCALE inside the kernel)
    //    + mask all-ones flag reduction (block (0,0,3))
    transpose_qkvo<<<dim3(EMB / 32, EMB / 32, 4), 256, 0, stream>>>(
        wq, wk, wv, wo, wqkvT, woT, mask, mflag);

    // 1) LN1: x -> act
    ln_kernel<<<MROWS, 256, 0, stream>>>(x, act, ln1_a, ln1_b);

    // 2) fused QKV: [4096,3072] -> Qb, Kb (natural), VTb (transposed)
    gemm_mfma<128, 2><<<dim3(3 * EMB / 128, MROWS / 128), 512, 0, stream>>>(
        act, wqkvT, Qb, nullptr, nullptr, MROWS, 3 * EMB, EMB, 0, 3, Kb, VTb);

    // 3) attention -> act
    attn_mfma<<<BATCH * NHEADS * (SEQ / 128), 512, 0, stream>>>(
        Qb, Kb, VTb, mask, mflag, act);

    // 4) h = attn @ wo + x -> d_out (fp32), BN=64 3-buffer counted-vmcnt
    gemm_mfma<64, 4><<<dim3(EMB / 64, MROWS / 128), 512, 0, stream>>>(
        act, woT, out, nullptr, x, MROWS, EMB, EMB, 0, 1, nullptr, nullptr);

    // 5) LN2: h -> act
    ln_kernel<<<MROWS, 256, 0, stream>>>(out, act, ln2_a, ln2_b);

    // 6) FF1: f1 = relu(act @ ff1 + b1) (bf16), wide-tile 64x64/wave GEMM
    transpose_bf16<<<dim3(HID / 32, EMB / 32), 256, 0, stream>>>(ff1_w, ffT, EMB, HID);
    gemm_w64<<<dim3(HID / 128, MROWS / 128), 256, 0, stream>>>(
        act, ffT, f1, ff1_b, nullptr, MROWS, HID, EMB, 1, 0);

    // 7) FF2: out = f1 @ ff2 + b2 + h (in-place fp32 residual), wide-tile GEMM
    transpose_bf16<<<dim3(EMB / 32, HID / 32), 256, 0, stream>>>(ff2_w, ffT, HID, EMB);
    gemm_w64<<<dim3(EMB / 128, MROWS / 128), 256, 0, stream>>>(
        f1, ffT, out, ff2_b, out, MROWS, EMB, HID, 0, 1);
}

// Round 7
// 372.541 us; speedup vs baseline: 1.0208x; 1.0208x over previous
//
#include <hip/hip_runtime.h>
#include <stdint.h>

// Problem dims (fixed)
#define EMB 1024
#define HID 4096
#define NHEADS 16
#define DKH 64
#define SEQ 2048
#define BATCH 2
#define MROWS (BATCH * SEQ)  // 4096
#define GBK 64               // GEMM K-tile (128B LDS rows, 8x16B groups)

typedef unsigned short u16;
typedef unsigned int u32;
typedef __attribute__((ext_vector_type(8))) short short8;   // 8 bf16 (4 VGPRs)
typedef __attribute__((ext_vector_type(4))) float f32x4;    // MFMA 16x16 C/D
typedef __attribute__((ext_vector_type(16))) float f32x16;  // MFMA 32x32 C/D
typedef __attribute__((ext_vector_type(4))) u32 u32x4;
typedef __attribute__((ext_vector_type(2))) int i32x2;

// Softmax exp path: v_exp_f32 (=exp2) with log2e folded into Q weights.
#if __has_builtin(__builtin_amdgcn_exp2f)
#define QK_SCALE 0.18033688011f  // 0.125 * log2(e)
#define QK_CLAMP 43.3f           // 30 * log2(e)
__device__ __forceinline__ float pexp(float x) { return __builtin_amdgcn_exp2f(x); }
#else
#define QK_SCALE 0.125f
#define QK_CLAMP 30.0f
__device__ __forceinline__ float pexp(float x) { return __expf(x); }
#endif

__device__ __forceinline__ u16 f2bf(float f) {
    unsigned u = __float_as_uint(f);
    unsigned r = 0x7FFFu + ((u >> 16) & 1u);  // RNE
    return (u16)((u + r) >> 16);
}
__device__ __forceinline__ f32x4 mfma16(short8 a, short8 b, f32x4 c) {
    return __builtin_amdgcn_mfma_f32_16x16x32_bf16(a, b, c, 0, 0, 0);
}
__device__ __forceinline__ f32x16 mfma32(short8 a, short8 b, f32x16 c) {
    return __builtin_amdgcn_mfma_f32_32x32x16_bf16(a, b, c, 0, 0, 0);
}
// Async global->LDS, 16B/lane. LDS dest = wave-uniform base + lane*16.
__device__ __forceinline__ void gl_lds16(const u16* g, u16* l) {
    __builtin_amdgcn_global_load_lds(
        (__attribute__((address_space(1))) void*)g,
        (__attribute__((address_space(3))) void*)l, 16, 0, 0);
}
// lane l<32 keeps a, gets partner's b; lane l>=32 keeps b, gets partner's a.
__device__ __forceinline__ void plswap(u32& a, u32& b) {
#if __has_builtin(__builtin_amdgcn_permlane32_swap)
    i32x2 r = __builtin_amdgcn_permlane32_swap((int)a, (int)b, false, false);
    a = (u32)r.x; b = (u32)r.y;
#else
    const u32 ta = (u32)__shfl_xor((int)a, 32);
    const u32 tb = (u32)__shfl_xor((int)b, 32);
    const bool hi = (threadIdx.x & 32) != 0;
    const u32 na = hi ? tb : a;
    const u32 nb = hi ? b : ta;
    a = na; b = nb;
#endif
}
__device__ __forceinline__ short8 mk8(u32 a, u32 b, u32 c, u32 d) {
    u32x4 t; t.x = a; t.y = b; t.z = c; t.w = d;
    return __builtin_bit_cast(short8, t);
}

// ---------------------------------------------------------------------------
// Batched transpose + convert for the four 1024x1024 attention weights:
// z selects {wq,wk,wv,wo}; wq scaled by QK_SCALE (folds softmax scale into Q).
// Block (0,0,z=3) additionally reduces the mask to an "all ones" flag so the
// attention kernel can take a mask-free fast path (wave-uniform branch).
// ---------------------------------------------------------------------------
__global__ __launch_bounds__(256) void transpose_qkvo(
    const float* __restrict__ wq, const float* __restrict__ wk,
    const float* __restrict__ wv, const float* __restrict__ wo,
    u16* __restrict__ qkvT, u16* __restrict__ woT,
    const int* __restrict__ msk, int* __restrict__ flag) {
    __shared__ u16 t[32][33];
    const int z = blockIdx.z;
    const float* W = (z == 0) ? wq : (z == 1) ? wk : (z == 2) ? wv : wo;
    u16* WT = (z < 3) ? (qkvT + (size_t)z * EMB * EMB) : woT;
    const float scale = (z == 0) ? QK_SCALE : 1.0f;
    const int tx = threadIdx.x & 31, ty = threadIdx.x >> 5;
    const int k0 = blockIdx.y * 32, n0 = blockIdx.x * 32;
#pragma unroll
    for (int r = 0; r < 32; r += 8)
        t[ty + r][tx] = f2bf(scale * W[(size_t)(k0 + ty + r) * EMB + n0 + tx]);
    __syncthreads();
#pragma unroll
    for (int r = 0; r < 32; r += 8)
        WT[(size_t)(n0 + ty + r) * EMB + k0 + tx] = t[tx][ty + r];

    if (z == 3 && blockIdx.x == 0 && blockIdx.y == 0) {
        int v = 1;
        for (int i = threadIdx.x; i < BATCH * SEQ; i += 256)
            v &= (msk[i] != 0) ? 1 : 0;
        v = __all(v) ? 1 : 0;
        __shared__ int rr[4];
        if ((threadIdx.x & 63) == 0) rr[threadIdx.x >> 6] = v;
        __syncthreads();
        if (threadIdx.x == 0) flag[0] = rr[0] & rr[1] & rr[2] & rr[3];
    }
}

// ---------------------------------------------------------------------------
// Transpose + convert: W fp32 [K][N] -> WT bf16 [N][K]. 32x32 LDS tiles.
// ---------------------------------------------------------------------------
__global__ __launch_bounds__(256) void transpose_bf16(
    const float* __restrict__ W, u16* __restrict__ WT, int K, int N) {
    __shared__ u16 t[32][33];
    const int tx = threadIdx.x & 31, ty = threadIdx.x >> 5;  // ty 0..7
    const int k0 = blockIdx.y * 32, n0 = blockIdx.x * 32;
#pragma unroll
    for (int r = 0; r < 32; r += 8)
        t[ty + r][tx] = f2bf(W[(size_t)(k0 + ty + r) * N + n0 + tx]);
    __syncthreads();
#pragma unroll
    for (int r = 0; r < 32; r += 8)
        WT[(size_t)(n0 + ty + r) * K + k0 + tx] = t[tx][ty + r];
}

// ---------------------------------------------------------------------------
// LayerNorm: one block per row of 1024, fp32 in, bf16 out. Bessel var,
// denom (std+eps), scalar alpha/beta.
// ---------------------------------------------------------------------------
__global__ __launch_bounds__(256) void ln_kernel(
    const float* __restrict__ x, u16* __restrict__ out,
    const float* __restrict__ alpha_p, const float* __restrict__ beta_p) {
    const int row = blockIdx.x;
    const int tid = threadIdx.x;
    float4 v = reinterpret_cast<const float4*>(x + (size_t)row * EMB)[tid];

    __shared__ float red[4];
    float s = v.x + v.y + v.z + v.w;
    for (int off = 32; off; off >>= 1) s += __shfl_down(s, off);
    if ((tid & 63) == 0) red[tid >> 6] = s;
    __syncthreads();
    float mean = (red[0] + red[1] + red[2] + red[3]) * (1.0f / EMB);
    __syncthreads();

    float d0 = v.x - mean, d1 = v.y - mean, d2 = v.z - mean, d3 = v.w - mean;
    float sq = d0 * d0 + d1 * d1 + d2 * d2 + d3 * d3;
    for (int off = 32; off; off >>= 1) sq += __shfl_down(sq, off);
    if ((tid & 63) == 0) red[tid >> 6] = sq;
    __syncthreads();
    float var = (red[0] + red[1] + red[2] + red[3]) * (1.0f / (EMB - 1));
    float inv = 1.0f / (sqrtf(var) + 1e-6f);
    float a = alpha_p[0], b = beta_p[0];

    ushort4 o;
    o.x = f2bf(a * d0 * inv + b);
    o.y = f2bf(a * d1 * inv + b);
    o.z = f2bf(a * d2 * inv + b);
    o.w = f2bf(a * d3 * inv + b);
    reinterpret_cast<ushort4*>(out + (size_t)row * EMB)[tid] = o;
}

// ---------------------------------------------------------------------------
// MFMA GEMM, 512 threads (8 waves). C[M,N] = A[M,K] @ B[K,N], B transposed
// bf16 (BT [N][K]). 128 x BN tile. LDS rows 128B = 8x16B groups, group g at
// slot g^(row&7) (swizzle folded into the global source address) -> frag
// ds_read_b128 2-way = free.
//
// Pipeline (NBUF):
//  - BN==128: 2-buffer, one __syncthreads()/K-step. 64 KB LDS.
//  - BN==64: 3-buffer, COUNTED vmcnt (2 tiles in flight, never drained).
//    72 KB LDS, 2 blocks/CU.
//
// XCD remap: bid&7 = XCD; requires gridDim.y % 8 == 0 (here ny=32).
// out_mode: 0 bf16 [M][N] | 1 fp32 [M][N] (+res may alias C) |
//           2 bf16 transposed [N][M] | 3 fused QKV (C=Q, Kb_out=K, VT_out=V^T).
// ---------------------------------------------------------------------------
template <int BN, int NWM>
__global__ __launch_bounds__(512) void gemm_mfma(
    const u16* __restrict__ A, const u16* __restrict__ BT, void* C,
    const float* __restrict__ bias, const void* res,
    int M, int N, int K, int relu, int out_mode,
    u16* __restrict__ Kb_out, u16* __restrict__ VT_out) {
    constexpr int NWN = 8 / NWM;
    constexpr int WM = 128 / (16 * NWM);
    constexpr int WN = BN / (16 * NWN);
    constexpr int NBUF = (BN == 64) ? 3 : 2;
    __shared__ u16 As[NBUF][128][GBK];   // NBUF x 16 KB
    __shared__ u16 Bs[NBUF][BN][GBK];    // NBUF x (8|16) KB

    const int tid = threadIdx.x;
    const int wave = tid >> 6, lane = tid & 63;
    const int quad = lane >> 4, lc = lane & 15;
    const int wm = wave % NWM, wn = wave / NWM;

    // XCD-aware remap (speed-only heuristic)
    const int nx = gridDim.x;
    const int bid = blockIdx.y * nx + blockIdx.x;
    const int xcd = bid & 7, sl = bid >> 3;
    const int nyx = gridDim.y >> 3;
    const int bcol = sl % nx;
    const int brow = (sl / nx) + xcd * nyx;
    const int row0 = brow * 128, col0 = bcol * BN;

    // Staging lane map: 8 rows per instr; swizzled global group.
    const int srow = lane >> 3;            // 0..7
    const int scg = (lane & 7) ^ srow;     // global 16B-group for this lane

    f32x4 acc[WM][WN] = {};

    auto stage = [&](int k0, int buf) {
#pragma unroll
        for (int i = 0; i < 2; ++i) {      // A: 128 rows, 8 waves x 2 instrs
            const int rb = wave * 16 + i * 8;
            gl_lds16(A + (size_t)(row0 + rb + srow) * K + k0 + scg * 8,
                     &As[buf][rb][0]);
        }
        if constexpr (BN == 128) {
#pragma unroll
            for (int i = 0; i < 2; ++i) {
                const int rb = wave * 16 + i * 8;
                gl_lds16(BT + (size_t)(col0 + rb + srow) * K + k0 + scg * 8,
                         &Bs[buf][rb][0]);
            }
        } else {                            // BN == 64: 1 instr/wave
            const int rb = wave * 8;
            gl_lds16(BT + (size_t)(col0 + rb + srow) * K + k0 + scg * 8,
                     &Bs[buf][rb][0]);
        }
    };

    auto compute = [&](int cur) {
#pragma unroll
        for (int s = 0; s < 2; ++s) {      // two K=32 substeps per BK=64
            short8 af[WM], bfv[WN];
#pragma unroll
            for (int i = 0; i < WM; ++i) {
                const int ar = wm * (16 * WM) + i * 16 + lc;
                af[i] = *reinterpret_cast<const short8*>(
                    &As[cur][ar][(((s * 4 + quad) ^ (ar & 7))) * 8]);
            }
#pragma unroll
            for (int j = 0; j < WN; ++j) {
                const int br = wn * (16 * WN) + j * 16 + lc;
                bfv[j] = *reinterpret_cast<const short8*>(
                    &Bs[cur][br][(((s * 4 + quad) ^ (br & 7))) * 8]);
            }
#pragma unroll
            for (int i = 0; i < WM; ++i)
#pragma unroll
                for (int j = 0; j < WN; ++j)
                    acc[i][j] = mfma16(af[i], bfv[j], acc[i][j]);
        }
    };

    if constexpr (NBUF == 2) {
        stage(0, 0);
        __syncthreads();                    // drain -> chunk 0 resident
        int cur = 0;
        for (int k0 = 0; k0 < K; k0 += GBK) {
            if (k0 + GBK < K) stage(k0 + GBK, cur ^ 1);  // prefetch, no wait
            compute(cur);
            __syncthreads();   // publishes prefetched chunk; ends reads of cur
            cur ^= 1;
        }
    } else {
        // 3-buffer counted-vmcnt pipeline (2 tiles always in flight).
        stage(0, 0);
        if (GBK < K) stage(GBK, 1);
        int cur = 0;
        for (int k0 = 0; k0 < K; k0 += GBK) {
            if (k0 + 2 * GBK < K) {
                int nb = cur + 2; if (nb >= 3) nb -= 3;
                stage(k0 + 2 * GBK, nb);    // overwrites buffer whose reads
            }                               // ended at last iter's barrier(b)
            const int rem = (K - k0) >> 6;  // tiles remaining incl. current
            if (rem > 2)       asm volatile("s_waitcnt vmcnt(6)" ::: "memory");
            else if (rem == 2) asm volatile("s_waitcnt vmcnt(3)" ::: "memory");
            else               asm volatile("s_waitcnt vmcnt(0)" ::: "memory");
            __builtin_amdgcn_s_barrier();           // (a) tile cur resident
            __builtin_amdgcn_sched_barrier(0);      // rule #18 fence
            compute(cur);
            __builtin_amdgcn_s_barrier();           // (b) reads of cur done
            cur = (cur == 2) ? 0 : cur + 1;
        }
    }

    // Resolve output target (mode 3: segment-uniform per block since BN<=1024).
    u16* Cb = (u16*)C;
    int mode = out_mode, ncols = N, lcol0 = col0;
    if (out_mode == 3) {
        const int seg = col0 >> 10;
        lcol0 = col0 & 1023;
        ncols = EMB;
        if (seg == 1) { Cb = Kb_out; mode = 0; }
        else if (seg == 2) { Cb = VT_out; mode = 2; }
        else { mode = 0; }
    }

    // Epilogue. C/D layout: col = lc, row = quad*4 + r.
#pragma unroll
    for (int j = 0; j < WN; ++j) {
        const int col = lcol0 + wn * (16 * WN) + j * 16 + lc;
        const float bv = bias ? bias[col] : 0.f;
#pragma unroll
        for (int i = 0; i < WM; ++i) {
            const int rbase = row0 + wm * (16 * WM) + i * 16 + quad * 4;
            if (mode == 2) {  // bf16 transposed [N][M]
                ushort4 o;
                o.x = f2bf(acc[i][j][0]); o.y = f2bf(acc[i][j][1]);
                o.z = f2bf(acc[i][j][2]); o.w = f2bf(acc[i][j][3]);
                *reinterpret_cast<ushort4*>(Cb + (size_t)col * M + rbase) = o;
            } else {
#pragma unroll
                for (int r = 0; r < 4; ++r) {
                    const size_t idx = (size_t)(rbase + r) * ncols + col;
                    float v = acc[i][j][r] + bv;
                    if (relu) v = fmaxf(v, 0.f);
                    if (res) v += ((const float*)res)[idx];
                    if (mode == 1) ((float*)C)[idx] = v;
                    else Cb[idx] = f2bf(v);
                }
            }
        }
    }
}

// ---------------------------------------------------------------------------
// Wide-tile FFN GEMM v2: 256 threads = 4 waves, 128x128 block tile, each
// wave owns a 64x64 output as a 4x4 grid of 16x16x32 MFMA fragments.
// Per BK=64 K-step a wave does 16 ds_read_b128 + 32 mfma16: LDS:MFMA cycle
// ratio ~1.5 (vs 2.7 for the 8-wave BN=64 config) -> MfmaUtil cap ~67%.
// CRITICAL (round-5 lesson): fragments are 16x16 (quad in the k-group,
// lc=lane&15 in the row) -> the proven ZERO-conflict read pattern. The
// 32x32-fragment variant of this kernel had only 2 k-groups across 32 rows
// per read = structural 4-way bank conflict (4.19M counted, 1.58x LDS
// slowdown). Same bytes moved, wrong lane->address shape.
// 2-buffer + counted vmcnt(8) (one 8-load tile in flight, never drained).
// 64 KB LDS -> 2 blocks/CU.
// out: fp32out ? fp32 [M][N] (+res may alias C) : bf16 [M][N]; bias; relu.
// XCD remap as in gemm_mfma (gridDim.y % 8 == 0).
// ---------------------------------------------------------------------------
__global__ __launch_bounds__(256) void gemm_w64(
    const u16* __restrict__ A, const u16* __restrict__ BT, void* C,
    const float* __restrict__ bias, const void* res,
    int M, int N, int K, int relu, int fp32out) {
    __shared__ u16 As[2][128][GBK];   // 2 x 16 KB
    __shared__ u16 Bs[2][128][GBK];   // 2 x 16 KB

    const int tid = threadIdx.x;
    const int wave = tid >> 6, lane = tid & 63;
    const int quad = lane >> 4, lc = lane & 15;
    const int wm = wave >> 1, wn = wave & 1;   // 2x2 wave grid, 64x64 each

    // XCD-aware remap
    const int nx = gridDim.x;
    const int bid = blockIdx.y * nx + blockIdx.x;
    const int xcd = bid & 7, sl = bid >> 3;
    const int nyx = gridDim.y >> 3;
    const int bcol = sl % nx;
    const int brow = (sl / nx) + xcd * nyx;
    const int row0 = brow * 128, col0 = bcol * 128;

    // Staging lane map: 8 rows/instr; swizzled global 16B-group.
    const int srow = lane >> 3;            // 0..7
    const int scg = (lane & 7) ^ srow;     // global group for this lane

    f32x4 acc[4][4] = {};

    auto stage = [&](int k0, int buf) {
#pragma unroll
        for (int i = 0; i < 4; ++i) {      // A: 128 rows, 4 waves x 4 instrs
            const int rb = wave * 32 + i * 8;
            gl_lds16(A + (size_t)(row0 + rb + srow) * K + k0 + scg * 8,
                     &As[buf][rb][0]);
        }
#pragma unroll
        for (int i = 0; i < 4; ++i) {      // B: 128 cols (BT rows)
            const int rb = wave * 32 + i * 8;
            gl_lds16(BT + (size_t)(col0 + rb + srow) * K + k0 + scg * 8,
                     &Bs[buf][rb][0]);
        }
    };

    const int nt = K >> 6;                 // BK=64 tiles
    stage(0, 0);
    int cur = 0;
    for (int t = 0; t < nt; ++t) {
        if (t + 1 < nt) {
            stage((t + 1) << 6, cur ^ 1);  // prefetch (reads of cur^1 ended
                                            // at last trailing barrier)
            asm volatile("s_waitcnt vmcnt(8)" ::: "memory");  // tile t landed
        } else {
            asm volatile("s_waitcnt vmcnt(0)" ::: "memory");
        }
        __builtin_amdgcn_s_barrier();           // (a) tile t resident
        __builtin_amdgcn_sched_barrier(0);      // rule #18 fence

#pragma unroll
        for (int s = 0; s < 2; ++s) {      // two K=32 substeps per BK=64
            short8 af[4], bfv[4];
#pragma unroll
            for (int i = 0; i < 4; ++i) {
                const int ar = wm * 64 + i * 16 + lc;
                af[i] = *reinterpret_cast<const short8*>(
                    &As[cur][ar][(((s * 4 + quad) ^ (ar & 7))) * 8]);
            }
#pragma unroll
            for (int j = 0; j < 4; ++j) {
                const int br = wn * 64 + j * 16 + lc;
                bfv[j] = *reinterpret_cast<const short8*>(
                    &Bs[cur][br][(((s * 4 + quad) ^ (br & 7))) * 8]);
            }
#pragma unroll
            for (int i = 0; i < 4; ++i)
#pragma unroll
                for (int j = 0; j < 4; ++j)
                    acc[i][j] = mfma16(af[i], bfv[j], acc[i][j]);
        }
        __builtin_amdgcn_s_barrier();           // (b) reads of cur done
        cur ^= 1;
    }

    // Epilogue. C/D layout: col = lc, row = quad*4 + r.
#pragma unroll
    for (int j = 0; j < 4; ++j) {
        const int col = col0 + wn * 64 + j * 16 + lc;
        const float bv = bias ? bias[col] : 0.f;
#pragma unroll
        for (int i = 0; i < 4; ++i) {
            const int rbase = row0 + wm * 64 + i * 16 + quad * 4;
#pragma unroll
            for (int r = 0; r < 4; ++r) {
                const size_t idx = (size_t)(rbase + r) * N + col;
                float v = acc[i][j][r] + bv;
                if (relu) v = fmaxf(v, 0.f);
                if (res) v += ((const float*)res)[idx];
                if (fp32out) ((float*)C)[idx] = v;
                else ((u16*)C)[idx] = f2bf(v);
            }
        }
    }
}

// ---------------------------------------------------------------------------
// MFMA flash attention v4: 32x32x16 MFMA, 512 threads = 8 waves =
// 4 query-tiles (32 q each) x 2 key-streams (split-K over the sequence).
// Chunk of 128 keys staged per iteration (double-buffered); stream s owns
// keys [s*64, s*64+64) of each chunk. Transposed scores St = K·Q^T: lane
// holds query lane&31 across all its score regs, so P needs only a
// lane<->lane+32 exchange: truncating v_perm bf16 pack + permlane32_swap
// (no LDS P round-trip at all). No online max (Q carries QK_SCALE incl.
// log2e; exp2; clamp). Mask fast path via precomputed all-ones flag.
// Streams merge O and softmax denominators through LDS at the end (legal
// because exp is absolute, not max-shifted). Grid: 512 blocks,
// bid&31 = b*16+h (XCD affinity per head), bid>>5 = 128-query block.
// ---------------------------------------------------------------------------
__global__ __launch_bounds__(512, 4) void attn_mfma(
    const u16* __restrict__ Q, const u16* __restrict__ K,
    const u16* __restrict__ VT, const int* __restrict__ mask,
    const int* __restrict__ mflag, u16* __restrict__ O) {
    const int tid = threadIdx.x;
    const int wave = tid >> 6, lane = tid & 63;
    const int hi = lane >> 5, ln31 = lane & 31;
    const int qt = wave >> 1, s = wave & 1;
    const int H = blockIdx.x & 31;         // b*16+h
    const int qblk = blockIdx.x >> 5;      // 0..15
    const int h = H & 15, b = H >> 4;

    // LDS arena (64 KB): main loop uses Ks+Vs; epilogue aliases Om+Ls.
    __shared__ __align__(16) char smem[65536];
    u16 (*Ks)[128][DKH] = (u16(*)[128][DKH])smem;          // [2][128][64]
    u16 (*Vs)[DKH][128] = (u16(*)[DKH][128])(smem + 32768);  // [2][64][128]

    const int fast = mflag[0];

    // Q as B-operand frags: B[k = f*16 + hi*8 + j][n = q = ln31]
    const u16* qp = Q + (size_t)(b * SEQ + qblk * 128 + qt * 32 + ln31) * EMB
                      + h * DKH + hi * 8;
    short8 qb[4];
#pragma unroll
    for (int f = 0; f < 4; ++f)
        qb[f] = *reinterpret_cast<const short8*>(qp + f * 16);

    // Staging lane maps (swizzle folded into GLOBAL source; LDS dest linear).
    const int srow = lane >> 3, scg = (lane & 7) ^ srow;   // K: 8 tok/instr
    const int svr = lane >> 4, ssl = lane & 15;            // V: 4 dim/instr

    auto stage = [&](int kc, int buf) {
#pragma unroll
        for (int i = 0; i < 2; ++i) {      // K: 128 tokens, 8 waves x 2
            const int t8 = wave * 16 + i * 8;
            gl_lds16(K + (size_t)(b * SEQ + kc + t8 + srow) * EMB + h * DKH + scg * 8,
                     &Ks[buf][t8][0]);
        }
#pragma unroll
        for (int i = 0; i < 2; ++i) {      // V^T: 64 dims, 8 waves x 2
            const int d4 = wave * 8 + i * 4;
            const int dim = d4 + svr;
            const int gv = ssl ^ (dim & 15);
            gl_lds16(VT + (size_t)(h * DKH + dim) * MROWS + b * SEQ + kc + gv * 8,
                     &Vs[buf][d4][0]);
        }
    };

    f32x16 o0 = {}, o1 = {};   // O[q=row][dim], n-tiles dim 0-31 / 32-63
    float rs = 0.f;            // partial denom for query ln31 (this stream)
    const int tok0 = s * 64;   // this wave's key base within the 128-chunk

    stage(0, 0);
    __syncthreads();
    int cur = 0;

    for (int kc = 0; kc < SEQ; kc += 128) {
        if (kc + 128 < SEQ) stage(kc + 128, cur ^ 1);  // prefetch, no wait

#pragma unroll
        for (int mt = 0; mt < 2; ++mt) {   // two 32-key m-tiles
            const int trow = tok0 + mt * 32 + ln31;
            f32x16 st = {};
#pragma unroll
            for (int f = 0; f < 4; ++f) {  // K-dim 64 = 4 steps of 16
                const int slot = (2 * f + hi) ^ (trow & 7);
                const short8 ka = *reinterpret_cast<const short8*>(
                    &Ks[cur][trow][slot * 8]);
                st = mfma32(ka, qb[f], st);
            }
            // st[r]: score(key = mt*32 + (r&3)+8*(r>>2)+4*hi, query = ln31)
            if (fast) {
#pragma unroll
                for (int r = 0; r < 16; ++r)
                    st[r] = pexp(fminf(st[r], QK_CLAMP));
            } else {
#pragma unroll
                for (int g = 0; g < 4; ++g) {
                    const int4 mk = *reinterpret_cast<const int4*>(
                        mask + b * SEQ + kc + tok0 + mt * 32 + g * 8 + hi * 4);
                    const int* mkp = &mk.x;
#pragma unroll
                    for (int r4 = 0; r4 < 4; ++r4) {
                        const int r = g * 4 + r4;
                        const float pv = pexp(fminf(st[r], QK_CLAMP));
                        st[r] = mkp[r4] ? pv : 0.f;
                    }
                }
            }
            rs += (((st[0] + st[1]) + (st[2] + st[3])) +
                   ((st[4] + st[5]) + (st[6] + st[7]))) +
                  (((st[8] + st[9]) + (st[10] + st[11])) +
                   ((st[12] + st[13]) + (st[14] + st[15])));

            // Truncating bf16 pack of adjacent-key pairs, then lane<->lane+32
            // swaps build the PV A-frags (A[m=q=ln31][k=hi*8+j]) in-register.
            u32 pk0 = __builtin_amdgcn_perm(__float_as_uint(st[1]),
                                            __float_as_uint(st[0]), 0x07060302u);
            u32 pk1 = __builtin_amdgcn_perm(__float_as_uint(st[3]),
                                            __float_as_uint(st[2]), 0x07060302u);
            u32 pk2 = __builtin_amdgcn_perm(__float_as_uint(st[5]),
                                            __float_as_uint(st[4]), 0x07060302u);
            u32 pk3 = __builtin_amdgcn_perm(__float_as_uint(st[7]),
                                            __float_as_uint(st[6]), 0x07060302u);
            u32 pk4 = __builtin_amdgcn_perm(__float_as_uint(st[9]),
                                            __float_as_uint(st[8]), 0x07060302u);
            u32 pk5 = __builtin_amdgcn_perm(__float_as_uint(st[11]),
                                            __float_as_uint(st[10]), 0x07060302u);
            u32 pk6 = __builtin_amdgcn_perm(__float_as_uint(st[13]),
                                            __float_as_uint(st[12]), 0x07060302u);
            u32 pk7 = __builtin_amdgcn_perm(__float_as_uint(st[15]),
                                            __float_as_uint(st[14]), 0x07060302u);
            plswap(pk0, pk2);   // pk0: lo keys(0,1)/hi(8,9); pk2: lo(4,5)/hi(12,13)
            plswap(pk1, pk3);
            plswap(pk4, pk6);
            plswap(pk5, pk7);
            const short8 fr0 = mk8(pk0, pk1, pk2, pk3);  // keys mt*32 +  0..15
            const short8 fr1 = mk8(pk4, pk5, pk6, pk7);  // keys mt*32 + 16..31

#pragma unroll
            for (int sub = 0; sub < 2; ++sub) {
                const short8 fr = sub ? fr1 : fr0;
                const int g = s * 8 + (2 * mt + sub) * 2 + hi;  // token 16B-group
#pragma unroll
                for (int nt = 0; nt < 2; ++nt) {
                    const int drow = nt * 32 + ln31;
                    const short8 vb = *reinterpret_cast<const short8*>(
                        &Vs[cur][drow][(g ^ (drow & 15)) * 8]);
                    if (nt == 0) o0 = mfma32(fr, vb, o0);
                    else         o1 = mfma32(fr, vb, o1);
                }
            }
        }
        __syncthreads();   // publishes prefetched chunk; ends reads of cur
        cur ^= 1;
    }

    // ---- merge the two key-streams of each query-tile via LDS ----
    rs += __shfl_xor(rs, 32);               // full stream-partial for query ln31

    float* Om = (float*)smem;               // [4][32][68] fp32 (padded rows)
    float* Ls = (float*)(smem + 34816);     // [128]

    if (s == 0) {
#pragma unroll
        for (int nt = 0; nt < 2; ++nt)
#pragma unroll
            for (int r = 0; r < 16; ++r) {
                const int row = (r & 3) + 8 * (r >> 2) + 4 * hi;
                Om[(qt * 32 + row) * 68 + nt * 32 + ln31] = nt ? o1[r] : o0[r];
            }
        if (lane < 32) Ls[qt * 32 + ln31] = rs;
    }
    __syncthreads();
    if (s == 1) {
        const float lt = rs + Ls[qt * 32 + ln31];
        if (lane < 32) Ls[qt * 32 + ln31] = lt;
#pragma unroll
        for (int nt = 0; nt < 2; ++nt)
#pragma unroll
            for (int r = 0; r < 16; ++r) {
                const int row = (r & 3) + 8 * (r >> 2) + 4 * hi;
                const int idx = (qt * 32 + row) * 68 + nt * 32 + ln31;
                Om[idx] += nt ? o1[r] : o0[r];
            }
    }
    __syncthreads();

    // ---- coalesced vectorized writeback: thread -> (q = tid>>2, seg) ----
    {
        const int q = tid >> 2, seg = tid & 3;
        const float inv = 1.0f / Ls[q];
        const float* src = Om + q * 68 + seg * 16;
        u16* dst = O + (size_t)(b * SEQ + qblk * 128 + q) * EMB + h * DKH + seg * 16;
#pragma unroll
        for (int i = 0; i < 4; ++i) {
            const float4 v = *reinterpret_cast<const float4*>(src + i * 4);
            ushort4 ou;
            ou.x = f2bf(v.x * inv); ou.y = f2bf(v.y * inv);
            ou.z = f2bf(v.z * inv); ou.w = f2bf(v.w * inv);
            *reinterpret_cast<ushort4*>(dst + i * 4) = ou;
        }
    }
}

// ---------------------------------------------------------------------------
// Orchestration. fp32 I/O, bf16 internals. ws (48 MB):
//   [0,8M)    act: xn -> attn_out -> xn2
//   [8,16M)   Q   --+
//   [16,24M)  K     +-- overlaid by f1 [8,40M) after attention
//   [24,32M)  VT  --+
//   [32M)     mask all-ones flag (int; dead once f1 is written)
//   [40,46M)  wqkvT [3072][1024]; [46,48M) woT --> later ffT [40,48M)
// h (fp32) lives in d_out (in-place residual in final GEMM).
// ---------------------------------------------------------------------------
extern "C" void kernel_launch(void* const* d_in, const int* in_sizes, int n_in,
                              void* d_out, int out_size, void* d_ws, size_t ws_size,
                              hipStream_t stream) {
    const float* x     = (const float*)d_in[0];
    const int*   mask  = (const int*)d_in[1];
    const float* wq    = (const float*)d_in[2];
    const float* wk    = (const float*)d_in[3];
    const float* wv    = (const float*)d_in[4];
    const float* wo    = (const float*)d_in[5];
    const float* ff1_w = (const float*)d_in[6];
    const float* ff1_b = (const float*)d_in[7];
    const float* ff2_w = (const float*)d_in[8];
    const float* ff2_b = (const float*)d_in[9];
    const float* ln1_a = (const float*)d_in[10];
    const float* ln1_b = (const float*)d_in[11];
    const float* ln2_a = (const float*)d_in[12];
    const float* ln2_b = (const float*)d_in[13];
    float* out = (float*)d_out;

    char* ws = (char*)d_ws;
    const size_t MB = 1u << 20;
    u16* act   = (u16*)(ws + 0);
    u16* Qb    = (u16*)(ws + 8 * MB);
    u16* Kb    = (u16*)(ws + 16 * MB);
    u16* VTb   = (u16*)(ws + 24 * MB);
    int* mflag = (int*)(ws + 32 * MB);   // free until f1 is written (step 6)
    u16* f1    = (u16*)(ws + 8 * MB);    // 32 MB, overlays Q/K/VT (dead)
    u16* wqkvT = (u16*)(ws + 40 * MB);   // [3*EMB][EMB] bf16 = 6 MB
    u16* woT   = (u16*)(ws + 46 * MB);   // 2 MB
    u16* ffT   = (u16*)(ws + 40 * MB);   // 8 MB rotating (ff1T, then ff2T)

    // 0) batched weight transposes (wq scaled by QK_SCALE inside the kernel)
    //    + mask all-ones flag reduction (block (0,0,3))
    transpose_qkvo<<<dim3(EMB / 32, EMB / 32, 4), 256, 0, stream>>>(
        wq, wk, wv, wo, wqkvT, woT, mask, mflag);

    // 1) LN1: x -> act
    ln_kernel<<<MROWS, 256, 0, stream>>>(x, act, ln1_a, ln1_b);

    // 2) fused QKV: [4096,3072] -> Qb, Kb (natural), VTb (transposed)
    gemm_mfma<128, 2><<<dim3(3 * EMB / 128, MROWS / 128), 512, 0, stream>>>(
        act, wqkvT, Qb, nullptr, nullptr, MROWS, 3 * EMB, EMB, 0, 3, Kb, VTb);

    // 3) attention -> act
    attn_mfma<<<BATCH * NHEADS * (SEQ / 128), 512, 0, stream>>>(
        Qb, Kb, VTb, mask, mflag, act);

    // 4) h = attn @ wo + x -> d_out (fp32), BN=64 3-buffer counted-vmcnt
    gemm_mfma<64, 4><<<dim3(EMB / 64, MROWS / 128), 512, 0, stream>>>(
        act, woT, out, nullptr, x, MROWS, EMB, EMB, 0, 1, nullptr, nullptr);

    // 5) LN2: h -> act
    ln_kernel<<<MROWS, 256, 0, stream>>>(out, act, ln2_a, ln2_b);

    // 6) FF1: f1 = relu(act @ ff1 + b1) (bf16), 64x64/wave 16x16-frag GEMM
    transpose_bf16<<<dim3(HID / 32, EMB / 32), 256, 0, stream>>>(ff1_w, ffT, EMB, HID);
    gemm_w64<<<dim3(HID / 128, MROWS / 128), 256, 0, stream>>>(
        act, ffT, f1, ff1_b, nullptr, MROWS, HID, EMB, 1, 0);

    // 7) FF2: out = f1 @ ff2 + b2 + h (in-place fp32 residual), same GEMM
    transpose_bf16<<<dim3(EMB / 32, HID / 32), 256, 0, stream>>>(ff2_w, ffT, HID, EMB);
    gemm_w64<<<dim3(EMB / 128, MROWS / 128), 256, 0, stream>>>(
        f1, ffT, out, ff2_b, out, MROWS, EMB, HID, 0, 1);
}

// Round 8
// 351.563 us; speedup vs baseline: 1.0817x; 1.0597x over previous
//
#include <hip/hip_runtime.h>
#include <stdint.h>

// Problem dims (fixed)
#define EMB 1024
#define HID 4096
#define NHEADS 16
#define DKH 64
#define SEQ 2048
#define BATCH 2
#define MROWS (BATCH * SEQ)  // 4096
#define GBK 64               // GEMM K-tile (128B LDS rows, 8x16B groups)

typedef unsigned short u16;
typedef unsigned int u32;
typedef __attribute__((ext_vector_type(8))) short short8;   // 8 bf16 (4 VGPRs)
typedef __attribute__((ext_vector_type(4))) float f32x4;    // MFMA 16x16 C/D
typedef __attribute__((ext_vector_type(16))) float f32x16;  // MFMA 32x32 C/D
typedef __attribute__((ext_vector_type(4))) u32 u32x4;
typedef __attribute__((ext_vector_type(2))) int i32x2;

// Softmax exp path: v_exp_f32 (=exp2) with log2e folded into Q weights.
#if __has_builtin(__builtin_amdgcn_exp2f)
#define QK_SCALE 0.18033688011f  // 0.125 * log2(e)
#define QK_CLAMP 43.3f           // 30 * log2(e)
__device__ __forceinline__ float pexp(float x) { return __builtin_amdgcn_exp2f(x); }
#else
#define QK_SCALE 0.125f
#define QK_CLAMP 30.0f
__device__ __forceinline__ float pexp(float x) { return __expf(x); }
#endif

__device__ __forceinline__ u16 f2bf(float f) {
    unsigned u = __float_as_uint(f);
    unsigned r = 0x7FFFu + ((u >> 16) & 1u);  // RNE
    return (u16)((u + r) >> 16);
}
__device__ __forceinline__ f32x4 mfma16(short8 a, short8 b, f32x4 c) {
    return __builtin_amdgcn_mfma_f32_16x16x32_bf16(a, b, c, 0, 0, 0);
}
__device__ __forceinline__ f32x16 mfma32(short8 a, short8 b, f32x16 c) {
    return __builtin_amdgcn_mfma_f32_32x32x16_bf16(a, b, c, 0, 0, 0);
}
// Async global->LDS, 16B/lane. LDS dest = wave-uniform base + lane*16.
__device__ __forceinline__ void gl_lds16(const u16* g, u16* l) {
    __builtin_amdgcn_global_load_lds(
        (__attribute__((address_space(1))) void*)g,
        (__attribute__((address_space(3))) void*)l, 16, 0, 0);
}
// lane l<32 keeps a, gets partner's b; lane l>=32 keeps b, gets partner's a.
__device__ __forceinline__ void plswap(u32& a, u32& b) {
#if __has_builtin(__builtin_amdgcn_permlane32_swap)
    i32x2 r = __builtin_amdgcn_permlane32_swap((int)a, (int)b, false, false);
    a = (u32)r.x; b = (u32)r.y;
#else
    const u32 ta = (u32)__shfl_xor((int)a, 32);
    const u32 tb = (u32)__shfl_xor((int)b, 32);
    const bool hi = (threadIdx.x & 32) != 0;
    const u32 na = hi ? tb : a;
    const u32 nb = hi ? b : ta;
    a = na; b = nb;
#endif
}
__device__ __forceinline__ short8 mk8(u32 a, u32 b, u32 c, u32 d) {
    u32x4 t; t.x = a; t.y = b; t.z = c; t.w = d;
    return __builtin_bit_cast(short8, t);
}

// ---------------------------------------------------------------------------
// Batched transpose + convert for the four 1024x1024 attention weights:
// z selects {wq,wk,wv,wo}; wq scaled by QK_SCALE (folds softmax scale into Q).
// Block (0,0,z=3) additionally reduces the mask to an "all ones" flag so the
// attention kernel can take a mask-free fast path (wave-uniform branch).
// ---------------------------------------------------------------------------
__global__ __launch_bounds__(256) void transpose_qkvo(
    const float* __restrict__ wq, const float* __restrict__ wk,
    const float* __restrict__ wv, const float* __restrict__ wo,
    u16* __restrict__ qkvT, u16* __restrict__ woT,
    const int* __restrict__ msk, int* __restrict__ flag) {
    __shared__ u16 t[32][33];
    const int z = blockIdx.z;
    const float* W = (z == 0) ? wq : (z == 1) ? wk : (z == 2) ? wv : wo;
    u16* WT = (z < 3) ? (qkvT + (size_t)z * EMB * EMB) : woT;
    const float scale = (z == 0) ? QK_SCALE : 1.0f;
    const int tx = threadIdx.x & 31, ty = threadIdx.x >> 5;
    const int k0 = blockIdx.y * 32, n0 = blockIdx.x * 32;
#pragma unroll
    for (int r = 0; r < 32; r += 8)
        t[ty + r][tx] = f2bf(scale * W[(size_t)(k0 + ty + r) * EMB + n0 + tx]);
    __syncthreads();
#pragma unroll
    for (int r = 0; r < 32; r += 8)
        WT[(size_t)(n0 + ty + r) * EMB + k0 + tx] = t[tx][ty + r];

    if (z == 3 && blockIdx.x == 0 && blockIdx.y == 0) {
        int v = 1;
        for (int i = threadIdx.x; i < BATCH * SEQ; i += 256)
            v &= (msk[i] != 0) ? 1 : 0;
        v = __all(v) ? 1 : 0;
        __shared__ int rr[4];
        if ((threadIdx.x & 63) == 0) rr[threadIdx.x >> 6] = v;
        __syncthreads();
        if (threadIdx.x == 0) flag[0] = rr[0] & rr[1] & rr[2] & rr[3];
    }
}

// ---------------------------------------------------------------------------
// Transpose + convert: W fp32 [K][N] -> WT bf16 [N][K]. 32x32 LDS tiles.
// ---------------------------------------------------------------------------
__global__ __launch_bounds__(256) void transpose_bf16(
    const float* __restrict__ W, u16* __restrict__ WT, int K, int N) {
    __shared__ u16 t[32][33];
    const int tx = threadIdx.x & 31, ty = threadIdx.x >> 5;  // ty 0..7
    const int k0 = blockIdx.y * 32, n0 = blockIdx.x * 32;
#pragma unroll
    for (int r = 0; r < 32; r += 8)
        t[ty + r][tx] = f2bf(W[(size_t)(k0 + ty + r) * N + n0 + tx]);
    __syncthreads();
#pragma unroll
    for (int r = 0; r < 32; r += 8)
        WT[(size_t)(n0 + ty + r) * K + k0 + tx] = t[tx][ty + r];
}

// ---------------------------------------------------------------------------
// LayerNorm: one block per row of 1024, fp32 in, bf16 out. Bessel var,
// denom (std+eps), scalar alpha/beta.
// ---------------------------------------------------------------------------
__global__ __launch_bounds__(256) void ln_kernel(
    const float* __restrict__ x, u16* __restrict__ out,
    const float* __restrict__ alpha_p, const float* __restrict__ beta_p) {
    const int row = blockIdx.x;
    const int tid = threadIdx.x;
    float4 v = reinterpret_cast<const float4*>(x + (size_t)row * EMB)[tid];

    __shared__ float red[4];
    float s = v.x + v.y + v.z + v.w;
    for (int off = 32; off; off >>= 1) s += __shfl_down(s, off);
    if ((tid & 63) == 0) red[tid >> 6] = s;
    __syncthreads();
    float mean = (red[0] + red[1] + red[2] + red[3]) * (1.0f / EMB);
    __syncthreads();

    float d0 = v.x - mean, d1 = v.y - mean, d2 = v.z - mean, d3 = v.w - mean;
    float sq = d0 * d0 + d1 * d1 + d2 * d2 + d3 * d3;
    for (int off = 32; off; off >>= 1) sq += __shfl_down(sq, off);
    if ((tid & 63) == 0) red[tid >> 6] = sq;
    __syncthreads();
    float var = (red[0] + red[1] + red[2] + red[3]) * (1.0f / (EMB - 1));
    float inv = 1.0f / (sqrtf(var) + 1e-6f);
    float a = alpha_p[0], b = beta_p[0];

    ushort4 o;
    o.x = f2bf(a * d0 * inv + b);
    o.y = f2bf(a * d1 * inv + b);
    o.z = f2bf(a * d2 * inv + b);
    o.w = f2bf(a * d3 * inv + b);
    reinterpret_cast<ushort4*>(out + (size_t)row * EMB)[tid] = o;
}

// ---------------------------------------------------------------------------
// MFMA GEMM, 512 threads (8 waves). C[M,N] = A[M,K] @ B[K,N], B transposed
// bf16 (BT [N][K]). 128 x BN tile. LDS rows 128B = 8x16B groups, group g at
// slot g^(row&7) (swizzle folded into the global source address) -> frag
// ds_read_b128 2-way = free.
//
// Pipeline (NBUF):
//  - BN==128: 2-buffer, one __syncthreads()/K-step. 64 KB LDS.
//  - BN==64: 3-buffer, COUNTED vmcnt (2 tiles in flight, never drained).
//    72 KB LDS, 2 blocks/CU.
//
// XCD remap: bid&7 = XCD; requires gridDim.y % 8 == 0 (here ny=32).
// out_mode: 0 bf16 [M][N] | 1 fp32 [M][N] (+res may alias C) |
//           2 bf16 transposed [N][M] | 3 fused QKV (C=Q, Kb_out=K, VT_out=V^T).
// ---------------------------------------------------------------------------
template <int BN, int NWM>
__global__ __launch_bounds__(512) void gemm_mfma(
    const u16* __restrict__ A, const u16* __restrict__ BT, void* C,
    const float* __restrict__ bias, const void* res,
    int M, int N, int K, int relu, int out_mode,
    u16* __restrict__ Kb_out, u16* __restrict__ VT_out) {
    constexpr int NWN = 8 / NWM;
    constexpr int WM = 128 / (16 * NWM);
    constexpr int WN = BN / (16 * NWN);
    constexpr int NBUF = (BN == 64) ? 3 : 2;
    __shared__ u16 As[NBUF][128][GBK];   // NBUF x 16 KB
    __shared__ u16 Bs[NBUF][BN][GBK];    // NBUF x (8|16) KB

    const int tid = threadIdx.x;
    const int wave = tid >> 6, lane = tid & 63;
    const int quad = lane >> 4, lc = lane & 15;
    const int wm = wave % NWM, wn = wave / NWM;

    // XCD-aware remap (speed-only heuristic)
    const int nx = gridDim.x;
    const int bid = blockIdx.y * nx + blockIdx.x;
    const int xcd = bid & 7, sl = bid >> 3;
    const int nyx = gridDim.y >> 3;
    const int bcol = sl % nx;
    const int brow = (sl / nx) + xcd * nyx;
    const int row0 = brow * 128, col0 = bcol * BN;

    // Staging lane map: 8 rows per instr; swizzled global group.
    const int srow = lane >> 3;            // 0..7
    const int scg = (lane & 7) ^ srow;     // global 16B-group for this lane

    f32x4 acc[WM][WN] = {};

    auto stage = [&](int k0, int buf) {
#pragma unroll
        for (int i = 0; i < 2; ++i) {      // A: 128 rows, 8 waves x 2 instrs
            const int rb = wave * 16 + i * 8;
            gl_lds16(A + (size_t)(row0 + rb + srow) * K + k0 + scg * 8,
                     &As[buf][rb][0]);
        }
        if constexpr (BN == 128) {
#pragma unroll
            for (int i = 0; i < 2; ++i) {
                const int rb = wave * 16 + i * 8;
                gl_lds16(BT + (size_t)(col0 + rb + srow) * K + k0 + scg * 8,
                         &Bs[buf][rb][0]);
            }
        } else {                            // BN == 64: 1 instr/wave
            const int rb = wave * 8;
            gl_lds16(BT + (size_t)(col0 + rb + srow) * K + k0 + scg * 8,
                     &Bs[buf][rb][0]);
        }
    };

    auto compute = [&](int cur) {
#pragma unroll
        for (int s = 0; s < 2; ++s) {      // two K=32 substeps per BK=64
            short8 af[WM], bfv[WN];
#pragma unroll
            for (int i = 0; i < WM; ++i) {
                const int ar = wm * (16 * WM) + i * 16 + lc;
                af[i] = *reinterpret_cast<const short8*>(
                    &As[cur][ar][(((s * 4 + quad) ^ (ar & 7))) * 8]);
            }
#pragma unroll
            for (int j = 0; j < WN; ++j) {
                const int br = wn * (16 * WN) + j * 16 + lc;
                bfv[j] = *reinterpret_cast<const short8*>(
                    &Bs[cur][br][(((s * 4 + quad) ^ (br & 7))) * 8]);
            }
#pragma unroll
            for (int i = 0; i < WM; ++i)
#pragma unroll
                for (int j = 0; j < WN; ++j)
                    acc[i][j] = mfma16(af[i], bfv[j], acc[i][j]);
        }
    };

    if constexpr (NBUF == 2) {
        stage(0, 0);
        __syncthreads();                    // drain -> chunk 0 resident
        int cur = 0;
        for (int k0 = 0; k0 < K; k0 += GBK) {
            if (k0 + GBK < K) stage(k0 + GBK, cur ^ 1);  // prefetch, no wait
            compute(cur);
            __syncthreads();   // publishes prefetched chunk; ends reads of cur
            cur ^= 1;
        }
    } else {
        // 3-buffer counted-vmcnt pipeline (2 tiles always in flight).
        stage(0, 0);
        if (GBK < K) stage(GBK, 1);
        int cur = 0;
        for (int k0 = 0; k0 < K; k0 += GBK) {
            if (k0 + 2 * GBK < K) {
                int nb = cur + 2; if (nb >= 3) nb -= 3;
                stage(k0 + 2 * GBK, nb);    // overwrites buffer whose reads
            }                               // ended at last iter's barrier(b)
            const int rem = (K - k0) >> 6;  // tiles remaining incl. current
            if (rem > 2)       asm volatile("s_waitcnt vmcnt(6)" ::: "memory");
            else if (rem == 2) asm volatile("s_waitcnt vmcnt(3)" ::: "memory");
            else               asm volatile("s_waitcnt vmcnt(0)" ::: "memory");
            __builtin_amdgcn_s_barrier();           // (a) tile cur resident
            __builtin_amdgcn_sched_barrier(0);      // rule #18 fence
            compute(cur);
            __builtin_amdgcn_s_barrier();           // (b) reads of cur done
            cur = (cur == 2) ? 0 : cur + 1;
        }
    }

    // Resolve output target (mode 3: segment-uniform per block since BN<=1024).
    u16* Cb = (u16*)C;
    int mode = out_mode, ncols = N, lcol0 = col0;
    if (out_mode == 3) {
        const int seg = col0 >> 10;
        lcol0 = col0 & 1023;
        ncols = EMB;
        if (seg == 1) { Cb = Kb_out; mode = 0; }
        else if (seg == 2) { Cb = VT_out; mode = 2; }
        else { mode = 0; }
    }

    // Epilogue. C/D layout: col = lc, row = quad*4 + r.
#pragma unroll
    for (int j = 0; j < WN; ++j) {
        const int col = lcol0 + wn * (16 * WN) + j * 16 + lc;
        const float bv = bias ? bias[col] : 0.f;
#pragma unroll
        for (int i = 0; i < WM; ++i) {
            const int rbase = row0 + wm * (16 * WM) + i * 16 + quad * 4;
            if (mode == 2) {  // bf16 transposed [N][M]
                ushort4 o;
                o.x = f2bf(acc[i][j][0]); o.y = f2bf(acc[i][j][1]);
                o.z = f2bf(acc[i][j][2]); o.w = f2bf(acc[i][j][3]);
                *reinterpret_cast<ushort4*>(Cb + (size_t)col * M + rbase) = o;
            } else {
#pragma unroll
                for (int r = 0; r < 4; ++r) {
                    const size_t idx = (size_t)(rbase + r) * ncols + col;
                    float v = acc[i][j][r] + bv;
                    if (relu) v = fmaxf(v, 0.f);
                    if (res) v += ((const float*)res)[idx];
                    if (mode == 1) ((float*)C)[idx] = v;
                    else Cb[idx] = f2bf(v);
                }
            }
        }
    }
}

// ---------------------------------------------------------------------------
// FFN GEMM v3 "wide-tile + K-stream split": 512 threads = 8 waves =
// 4 output positions (64x64 each, 2x2 over the 128x128 block tile) x
// 2 K-STREAMS. Stream s computes only substep s (k 0-31 / 32-63) of every
// shared BK=64 tile -> same LDS buffers/staging/barriers as the 4-wave
// variant, half the per-wave work, but 2x waves = 2 waves/SIMD even at
// 1 block/CU (fixes round-7's 1-wave/SIMD latency wall: 3060 cyc/K-step
// measured vs ~400 of issue work; OccupancyPercent was 10%).
// Per wave per K-step: 8 zero-conflict ds_read_b128 + 16 mfma16. Per CU:
// 96 KB LDS traffic (768 clk) vs 512 clk MFMA -> ~67% MfmaUtil cap.
// 2-buffer + counted vmcnt(4) (each wave's 4 stage loads of the NEXT tile
// stay in flight; never drained in-loop).
// End: stream pairs merge acc via LDS (reuses the 64 KB staging arena after
// the loop's trailing barrier), then a conflict-free, fully-coalesced flat
// epilogue (lane-contiguous float4) applies bias/relu/res and writes C.
// out: fp32out ? fp32 [M][N] (+res may alias C elementwise) : bf16 [M][N].
// XCD remap as in gemm_mfma (gridDim.y % 8 == 0). LDS 64 KB.
// ---------------------------------------------------------------------------
__global__ __launch_bounds__(512) void gemm_ws(
    const u16* __restrict__ A, const u16* __restrict__ BT, void* C,
    const float* __restrict__ bias, const void* res,
    int M, int N, int K, int relu, int fp32out) {
    __shared__ __align__(16) char smem[65536];
    u16 (*As)[128][GBK] = (u16(*)[128][GBK])smem;            // [2][128][64] 32 KB
    u16 (*Bs)[128][GBK] = (u16(*)[128][GBK])(smem + 32768);  // [2][128][64] 32 KB

    const int tid = threadIdx.x;
    const int wave = tid >> 6, lane = tid & 63;
    const int quad = lane >> 4, lc = lane & 15;
    const int p = wave >> 1, s = wave & 1;     // position, K-stream
    const int pm = p >> 1, pn = p & 1;         // 2x2 position grid

    // XCD-aware remap
    const int nx = gridDim.x;
    const int bid = blockIdx.y * nx + blockIdx.x;
    const int xcd = bid & 7, sl = bid >> 3;
    const int nyx = gridDim.y >> 3;
    const int bcol = sl % nx;
    const int brow = (sl / nx) + xcd * nyx;
    const int row0 = brow * 128, col0 = bcol * 128;

    // Staging lane map: 8 rows/instr; swizzled global 16B-group.
    const int srow = lane >> 3;
    const int scg = (lane & 7) ^ srow;

    f32x4 acc[4][4] = {};

    auto stage = [&](int k0, int buf) {
#pragma unroll
        for (int i = 0; i < 2; ++i) {          // A: 128 rows, 8 waves x 2
            const int rb = wave * 16 + i * 8;
            gl_lds16(A + (size_t)(row0 + rb + srow) * K + k0 + scg * 8,
                     &As[buf][rb][0]);
        }
#pragma unroll
        for (int i = 0; i < 2; ++i) {          // B: 128 cols (BT rows)
            const int rb = wave * 16 + i * 8;
            gl_lds16(BT + (size_t)(col0 + rb + srow) * K + k0 + scg * 8,
                     &Bs[buf][rb][0]);
        }
    };

    const int nt = K >> 6;
    stage(0, 0);
    int cur = 0;
    for (int t = 0; t < nt; ++t) {
        if (t + 1 < nt) {
            stage((t + 1) << 6, cur ^ 1);      // prefetch next tile
            asm volatile("s_waitcnt vmcnt(4)" ::: "memory");  // tile t landed
        } else {
            asm volatile("s_waitcnt vmcnt(0)" ::: "memory");
        }
        __builtin_amdgcn_s_barrier();           // (a) tile t resident
        __builtin_amdgcn_sched_barrier(0);      // rule #18 fence

        // This wave's substep only: k-groups s*4+quad (k = s*32..s*32+31).
        short8 af[4], bfv[4];
#pragma unroll
        for (int i = 0; i < 4; ++i) {
            const int ar = pm * 64 + i * 16 + lc;
            af[i] = *reinterpret_cast<const short8*>(
                &As[cur][ar][(((s * 4 + quad) ^ (ar & 7))) * 8]);
        }
#pragma unroll
        for (int j = 0; j < 4; ++j) {
            const int br = pn * 64 + j * 16 + lc;
            bfv[j] = *reinterpret_cast<const short8*>(
                &Bs[cur][br][(((s * 4 + quad) ^ (br & 7))) * 8]);
        }
#pragma unroll
        for (int i = 0; i < 4; ++i)
#pragma unroll
            for (int j = 0; j < 4; ++j)
                acc[i][j] = mfma16(af[i], bfv[j], acc[i][j]);

        __builtin_amdgcn_s_barrier();           // (b) reads of cur done
        cur ^= 1;
    }

    // ---- K-stream merge via LDS (overwrites staging; loop's trailing
    // barrier guarantees all As/Bs reads completed). C/D: row=quad*4+r, col=lc.
    float* Ms = (float*)smem;                   // [128][128] fp32 = 64 KB
    if (s == 0) {
#pragma unroll
        for (int i = 0; i < 4; ++i)
#pragma unroll
            for (int j = 0; j < 4; ++j)
#pragma unroll
                for (int r = 0; r < 4; ++r)
                    Ms[(pm * 64 + i * 16 + quad * 4 + r) * 128 +
                       pn * 64 + j * 16 + lc] = acc[i][j][r];
    }
    __syncthreads();
    if (s == 1) {
#pragma unroll
        for (int i = 0; i < 4; ++i)
#pragma unroll
            for (int j = 0; j < 4; ++j)
#pragma unroll
                for (int r = 0; r < 4; ++r)
                    Ms[(pm * 64 + i * 16 + quad * 4 + r) * 128 +
                       pn * 64 + j * 16 + lc] += acc[i][j][r];
    }
    __syncthreads();

    // ---- flat coalesced epilogue: lane-contiguous float4 LDS reads
    // (conflict-free), consecutive tids -> consecutive global 16B. ----
#pragma unroll
    for (int k = 0; k < 8; ++k) {
        const int fi = (k * 512 + tid) * 4;     // float index in [0,16384)
        const int row = fi >> 7, col = fi & 127;
        const float4 v = *reinterpret_cast<const float4*>(&Ms[fi]);
        float o0 = v.x, o1 = v.y, o2 = v.z, o3 = v.w;
        if (bias) {
            const float4 bv = *reinterpret_cast<const float4*>(&bias[col0 + col]);
            o0 += bv.x; o1 += bv.y; o2 += bv.z; o3 += bv.w;
        }
        if (relu) {
            o0 = fmaxf(o0, 0.f); o1 = fmaxf(o1, 0.f);
            o2 = fmaxf(o2, 0.f); o3 = fmaxf(o3, 0.f);
        }
        const size_t gidx = (size_t)(row0 + row) * N + col0 + col;
        if (res) {
            const float4 rv = *reinterpret_cast<const float4*>(
                &((const float*)res)[gidx]);
            o0 += rv.x; o1 += rv.y; o2 += rv.z; o3 += rv.w;
        }
        if (fp32out) {
            float4 ov; ov.x = o0; ov.y = o1; ov.z = o2; ov.w = o3;
            *reinterpret_cast<float4*>(&((float*)C)[gidx]) = ov;
        } else {
            ushort4 ov;
            ov.x = f2bf(o0); ov.y = f2bf(o1); ov.z = f2bf(o2); ov.w = f2bf(o3);
            *reinterpret_cast<ushort4*>(&((u16*)C)[gidx]) = ov;
        }
    }
}

// ---------------------------------------------------------------------------
// MFMA flash attention v4: 32x32x16 MFMA, 512 threads = 8 waves =
// 4 query-tiles (32 q each) x 2 key-streams (split-K over the sequence).
// Chunk of 128 keys staged per iteration (double-buffered); stream s owns
// keys [s*64, s*64+64) of each chunk. Transposed scores St = K·Q^T: lane
// holds query lane&31 across all its score regs, so P needs only a
// lane<->lane+32 exchange: truncating v_perm bf16 pack + permlane32_swap
// (no LDS P round-trip at all). No online max (Q carries QK_SCALE incl.
// log2e; exp2; clamp). Mask fast path via precomputed all-ones flag.
// Streams merge O and softmax denominators through LDS at the end (legal
// because exp is absolute, not max-shifted). Grid: 512 blocks,
// bid&31 = b*16+h (XCD affinity per head), bid>>5 = 128-query block.
// ---------------------------------------------------------------------------
__global__ __launch_bounds__(512, 4) void attn_mfma(
    const u16* __restrict__ Q, const u16* __restrict__ K,
    const u16* __restrict__ VT, const int* __restrict__ mask,
    const int* __restrict__ mflag, u16* __restrict__ O) {
    const int tid = threadIdx.x;
    const int wave = tid >> 6, lane = tid & 63;
    const int hi = lane >> 5, ln31 = lane & 31;
    const int qt = wave >> 1, s = wave & 1;
    const int H = blockIdx.x & 31;         // b*16+h
    const int qblk = blockIdx.x >> 5;      // 0..15
    const int h = H & 15, b = H >> 4;

    // LDS arena (64 KB): main loop uses Ks+Vs; epilogue aliases Om+Ls.
    __shared__ __align__(16) char smem[65536];
    u16 (*Ks)[128][DKH] = (u16(*)[128][DKH])smem;          // [2][128][64]
    u16 (*Vs)[DKH][128] = (u16(*)[DKH][128])(smem + 32768);  // [2][64][128]

    const int fast = mflag[0];

    // Q as B-operand frags: B[k = f*16 + hi*8 + j][n = q = ln31]
    const u16* qp = Q + (size_t)(b * SEQ + qblk * 128 + qt * 32 + ln31) * EMB
                      + h * DKH + hi * 8;
    short8 qb[4];
#pragma unroll
    for (int f = 0; f < 4; ++f)
        qb[f] = *reinterpret_cast<const short8*>(qp + f * 16);

    // Staging lane maps (swizzle folded into GLOBAL source; LDS dest linear).
    const int srow = lane >> 3, scg = (lane & 7) ^ srow;   // K: 8 tok/instr
    const int svr = lane >> 4, ssl = lane & 15;            // V: 4 dim/instr

    auto stage = [&](int kc, int buf) {
#pragma unroll
        for (int i = 0; i < 2; ++i) {      // K: 128 tokens, 8 waves x 2
            const int t8 = wave * 16 + i * 8;
            gl_lds16(K + (size_t)(b * SEQ + kc + t8 + srow) * EMB + h * DKH + scg * 8,
                     &Ks[buf][t8][0]);
        }
#pragma unroll
        for (int i = 0; i < 2; ++i) {      // V^T: 64 dims, 8 waves x 2
            const int d4 = wave * 8 + i * 4;
            const int dim = d4 + svr;
            const int gv = ssl ^ (dim & 15);
            gl_lds16(VT + (size_t)(h * DKH + dim) * MROWS + b * SEQ + kc + gv * 8,
                     &Vs[buf][d4][0]);
        }
    };

    f32x16 o0 = {}, o1 = {};   // O[q=row][dim], n-tiles dim 0-31 / 32-63
    float rs = 0.f;            // partial denom for query ln31 (this stream)
    const int tok0 = s * 64;   // this wave's key base within the 128-chunk

    stage(0, 0);
    __syncthreads();
    int cur = 0;

    for (int kc = 0; kc < SEQ; kc += 128) {
        if (kc + 128 < SEQ) stage(kc + 128, cur ^ 1);  // prefetch, no wait

#pragma unroll
        for (int mt = 0; mt < 2; ++mt) {   // two 32-key m-tiles
            const int trow = tok0 + mt * 32 + ln31;
            f32x16 st = {};
#pragma unroll
            for (int f = 0; f < 4; ++f) {  // K-dim 64 = 4 steps of 16
                const int slot = (2 * f + hi) ^ (trow & 7);
                const short8 ka = *reinterpret_cast<const short8*>(
                    &Ks[cur][trow][slot * 8]);
                st = mfma32(ka, qb[f], st);
            }
            // st[r]: score(key = mt*32 + (r&3)+8*(r>>2)+4*hi, query = ln31)
            if (fast) {
#pragma unroll
                for (int r = 0; r < 16; ++r)
                    st[r] = pexp(fminf(st[r], QK_CLAMP));
            } else {
#pragma unroll
                for (int g = 0; g < 4; ++g) {
                    const int4 mk = *reinterpret_cast<const int4*>(
                        mask + b * SEQ + kc + tok0 + mt * 32 + g * 8 + hi * 4);
                    const int* mkp = &mk.x;
#pragma unroll
                    for (int r4 = 0; r4 < 4; ++r4) {
                        const int r = g * 4 + r4;
                        const float pv = pexp(fminf(st[r], QK_CLAMP));
                        st[r] = mkp[r4] ? pv : 0.f;
                    }
                }
            }
            rs += (((st[0] + st[1]) + (st[2] + st[3])) +
                   ((st[4] + st[5]) + (st[6] + st[7]))) +
                  (((st[8] + st[9]) + (st[10] + st[11])) +
                   ((st[12] + st[13]) + (st[14] + st[15])));

            // Truncating bf16 pack of adjacent-key pairs, then lane<->lane+32
            // swaps build the PV A-frags (A[m=q=ln31][k=hi*8+j]) in-register.
            u32 pk0 = __builtin_amdgcn_perm(__float_as_uint(st[1]),
                                            __float_as_uint(st[0]), 0x07060302u);
            u32 pk1 = __builtin_amdgcn_perm(__float_as_uint(st[3]),
                                            __float_as_uint(st[2]), 0x07060302u);
            u32 pk2 = __builtin_amdgcn_perm(__float_as_uint(st[5]),
                                            __float_as_uint(st[4]), 0x07060302u);
            u32 pk3 = __builtin_amdgcn_perm(__float_as_uint(st[7]),
                                            __float_as_uint(st[6]), 0x07060302u);
            u32 pk4 = __builtin_amdgcn_perm(__float_as_uint(st[9]),
                                            __float_as_uint(st[8]), 0x07060302u);
            u32 pk5 = __builtin_amdgcn_perm(__float_as_uint(st[11]),
                                            __float_as_uint(st[10]), 0x07060302u);
            u32 pk6 = __builtin_amdgcn_perm(__float_as_uint(st[13]),
                                            __float_as_uint(st[12]), 0x07060302u);
            u32 pk7 = __builtin_amdgcn_perm(__float_as_uint(st[15]),
                                            __float_as_uint(st[14]), 0x07060302u);
            plswap(pk0, pk2);   // pk0: lo keys(0,1)/hi(8,9); pk2: lo(4,5)/hi(12,13)
            plswap(pk1, pk3);
            plswap(pk4, pk6);
            plswap(pk5, pk7);
            const short8 fr0 = mk8(pk0, pk1, pk2, pk3);  // keys mt*32 +  0..15
            const short8 fr1 = mk8(pk4, pk5, pk6, pk7);  // keys mt*32 + 16..31

#pragma unroll
            for (int sub = 0; sub < 2; ++sub) {
                const short8 fr = sub ? fr1 : fr0;
                const int g = s * 8 + (2 * mt + sub) * 2 + hi;  // token 16B-group
#pragma unroll
                for (int nt = 0; nt < 2; ++nt) {
                    const int drow = nt * 32 + ln31;
                    const short8 vb = *reinterpret_cast<const short8*>(
                        &Vs[cur][drow][(g ^ (drow & 15)) * 8]);
                    if (nt == 0) o0 = mfma32(fr, vb, o0);
                    else         o1 = mfma32(fr, vb, o1);
                }
            }
        }
        __syncthreads();   // publishes prefetched chunk; ends reads of cur
        cur ^= 1;
    }

    // ---- merge the two key-streams of each query-tile via LDS ----
    rs += __shfl_xor(rs, 32);               // full stream-partial for query ln31

    float* Om = (float*)smem;               // [4][32][68] fp32 (padded rows)
    float* Ls = (float*)(smem + 34816);     // [128]

    if (s == 0) {
#pragma unroll
        for (int nt = 0; nt < 2; ++nt)
#pragma unroll
            for (int r = 0; r < 16; ++r) {
                const int row = (r & 3) + 8 * (r >> 2) + 4 * hi;
                Om[(qt * 32 + row) * 68 + nt * 32 + ln31] = nt ? o1[r] : o0[r];
            }
        if (lane < 32) Ls[qt * 32 + ln31] = rs;
    }
    __syncthreads();
    if (s == 1) {
        const float lt = rs + Ls[qt * 32 + ln31];
        if (lane < 32) Ls[qt * 32 + ln31] = lt;
#pragma unroll
        for (int nt = 0; nt < 2; ++nt)
#pragma unroll
            for (int r = 0; r < 16; ++r) {
                const int row = (r & 3) + 8 * (r >> 2) + 4 * hi;
                const int idx = (qt * 32 + row) * 68 + nt * 32 + ln31;
                Om[idx] += nt ? o1[r] : o0[r];
            }
    }
    __syncthreads();

    // ---- coalesced vectorized writeback: thread -> (q = tid>>2, seg) ----
    {
        const int q = tid >> 2, seg = tid & 3;
        const float inv = 1.0f / Ls[q];
        const float* src = Om + q * 68 + seg * 16;
        u16* dst = O + (size_t)(b * SEQ + qblk * 128 + q) * EMB + h * DKH + seg * 16;
#pragma unroll
        for (int i = 0; i < 4; ++i) {
            const float4 v = *reinterpret_cast<const float4*>(src + i * 4);
            ushort4 ou;
            ou.x = f2bf(v.x * inv); ou.y = f2bf(v.y * inv);
            ou.z = f2bf(v.z * inv); ou.w = f2bf(v.w * inv);
            *reinterpret_cast<ushort4*>(dst + i * 4) = ou;
        }
    }
}

// ---------------------------------------------------------------------------
// Orchestration. fp32 I/O, bf16 internals. ws (48 MB):
//   [0,8M)    act: xn -> attn_out -> xn2
//   [8,16M)   Q   --+
//   [16,24M)  K     +-- overlaid by f1 [8,40M) after attention
//   [24,32M)  VT  --+
//   [32M)     mask all-ones flag (int; dead once f1 is written)
//   [40,46M)  wqkvT [3072][1024]; [46,48M) woT --> later ffT [40,48M)
// h (fp32) lives in d_out (in-place residual in final GEMM).
// ---------------------------------------------------------------------------
extern "C" void kernel_launch(void* const* d_in, const int* in_sizes, int n_in,
                              void* d_out, int out_size, void* d_ws, size_t ws_size,
                              hipStream_t stream) {
    const float* x     = (const float*)d_in[0];
    const int*   mask  = (const int*)d_in[1];
    const float* wq    = (const float*)d_in[2];
    const float* wk    = (const float*)d_in[3];
    const float* wv    = (const float*)d_in[4];
    const float* wo    = (const float*)d_in[5];
    const float* ff1_w = (const float*)d_in[6];
    const float* ff1_b = (const float*)d_in[7];
    const float* ff2_w = (const float*)d_in[8];
    const float* ff2_b = (const float*)d_in[9];
    const float* ln1_a = (const float*)d_in[10];
    const float* ln1_b = (const float*)d_in[11];
    const float* ln2_a = (const float*)d_in[12];
    const float* ln2_b = (const float*)d_in[13];
    float* out = (float*)d_out;

    char* ws = (char*)d_ws;
    const size_t MB = 1u << 20;
    u16* act   = (u16*)(ws + 0);
    u16* Qb    = (u16*)(ws + 8 * MB);
    u16* Kb    = (u16*)(ws + 16 * MB);
    u16* VTb   = (u16*)(ws + 24 * MB);
    int* mflag = (int*)(ws + 32 * MB);   // free until f1 is written (step 6)
    u16* f1    = (u16*)(ws + 8 * MB);    // 32 MB, overlays Q/K/VT (dead)
    u16* wqkvT = (u16*)(ws + 40 * MB);   // [3*EMB][EMB] bf16 = 6 MB
    u16* woT   = (u16*)(ws + 46 * MB);   // 2 MB
    u16* ffT   = (u16*)(ws + 40 * MB);   // 8 MB rotating (ff1T, then ff2T)

    // 0) batched weight transposes (wq scaled by QK_SCALE inside the kernel)
    //    + mask all-ones flag reduction (block (0,0,3))
    transpose_qkvo<<<dim3(EMB / 32, EMB / 32, 4), 256, 0, stream>>>(
        wq, wk, wv, wo, wqkvT, woT, mask, mflag);

    // 1) LN1: x -> act
    ln_kernel<<<MROWS, 256, 0, stream>>>(x, act, ln1_a, ln1_b);

    // 2) fused QKV: [4096,3072] -> Qb, Kb (natural), VTb (transposed)
    gemm_mfma<128, 2><<<dim3(3 * EMB / 128, MROWS / 128), 512, 0, stream>>>(
        act, wqkvT, Qb, nullptr, nullptr, MROWS, 3 * EMB, EMB, 0, 3, Kb, VTb);

    // 3) attention -> act
    attn_mfma<<<BATCH * NHEADS * (SEQ / 128), 512, 0, stream>>>(
        Qb, Kb, VTb, mask, mflag, act);

    // 4) h = attn @ wo + x -> d_out (fp32), BN=64 3-buffer counted-vmcnt
    gemm_mfma<64, 4><<<dim3(EMB / 64, MROWS / 128), 512, 0, stream>>>(
        act, woT, out, nullptr, x, MROWS, EMB, EMB, 0, 1, nullptr, nullptr);

    // 5) LN2: h -> act
    ln_kernel<<<MROWS, 256, 0, stream>>>(out, act, ln2_a, ln2_b);

    // 6) FF1: f1 = relu(act @ ff1 + b1) (bf16), K-stream-split wide GEMM
    transpose_bf16<<<dim3(HID / 32, EMB / 32), 256, 0, stream>>>(ff1_w, ffT, EMB, HID);
    gemm_ws<<<dim3(HID / 128, MROWS / 128), 512, 0, stream>>>(
        act, ffT, f1, ff1_b, nullptr, MROWS, HID, EMB, 1, 0);

    // 7) FF2: out = f1 @ ff2 + b2 + h (in-place fp32 residual), same GEMM
    transpose_bf16<<<dim3(EMB / 32, HID / 32), 256, 0, stream>>>(ff2_w, ffT, HID, EMB);
    gemm_ws<<<dim3(EMB / 128, MROWS / 128), 512, 0, stream>>>(
        f1, ffT, out, ff2_b, out, MROWS, EMB, HID, 0, 1);
}

// Round 9
// 338.710 us; speedup vs baseline: 1.1227x; 1.0379x over previous
//
#include <hip/hip_runtime.h>
#include <stdint.h>

// Problem dims (fixed)
#define EMB 1024
#define HID 4096
#define NHEADS 16
#define DKH 64
#define SEQ 2048
#define BATCH 2
#define MROWS (BATCH * SEQ)  // 4096
#define GBK 64               // GEMM K-tile (128B LDS rows, 8x16B groups)

typedef unsigned short u16;
typedef unsigned int u32;
typedef __attribute__((ext_vector_type(8))) short short8;   // 8 bf16 (4 VGPRs)
typedef __attribute__((ext_vector_type(4))) float f32x4;    // MFMA 16x16 C/D
typedef __attribute__((ext_vector_type(16))) float f32x16;  // MFMA 32x32 C/D
typedef __attribute__((ext_vector_type(4))) u32 u32x4;
typedef __attribute__((ext_vector_type(2))) int i32x2;

// Softmax exp path: v_exp_f32 (=exp2) with log2e folded into Q weights.
#if __has_builtin(__builtin_amdgcn_exp2f)
#define QK_SCALE 0.18033688011f  // 0.125 * log2(e)
#define QK_CLAMP 43.3f           // 30 * log2(e)
__device__ __forceinline__ float pexp(float x) { return __builtin_amdgcn_exp2f(x); }
#else
#define QK_SCALE 0.125f
#define QK_CLAMP 30.0f
__device__ __forceinline__ float pexp(float x) { return __expf(x); }
#endif

__device__ __forceinline__ u16 f2bf(float f) {
    unsigned u = __float_as_uint(f);
    unsigned r = 0x7FFFu + ((u >> 16) & 1u);  // RNE
    return (u16)((u + r) >> 16);
}
__device__ __forceinline__ f32x4 mfma16(short8 a, short8 b, f32x4 c) {
    return __builtin_amdgcn_mfma_f32_16x16x32_bf16(a, b, c, 0, 0, 0);
}
__device__ __forceinline__ f32x16 mfma32(short8 a, short8 b, f32x16 c) {
    return __builtin_amdgcn_mfma_f32_32x32x16_bf16(a, b, c, 0, 0, 0);
}
// Async global->LDS, 16B/lane. LDS dest = wave-uniform base + lane*16.
__device__ __forceinline__ void gl_lds16(const u16* g, u16* l) {
    __builtin_amdgcn_global_load_lds(
        (__attribute__((address_space(1))) void*)g,
        (__attribute__((address_space(3))) void*)l, 16, 0, 0);
}
// lane l<32 keeps a, gets partner's b; lane l>=32 keeps b, gets partner's a.
__device__ __forceinline__ void plswap(u32& a, u32& b) {
#if __has_builtin(__builtin_amdgcn_permlane32_swap)
    i32x2 r = __builtin_amdgcn_permlane32_swap((int)a, (int)b, false, false);
    a = (u32)r.x; b = (u32)r.y;
#else
    const u32 ta = (u32)__shfl_xor((int)a, 32);
    const u32 tb = (u32)__shfl_xor((int)b, 32);
    const bool hi = (threadIdx.x & 32) != 0;
    const u32 na = hi ? tb : a;
    const u32 nb = hi ? b : ta;
    a = na; b = nb;
#endif
}
__device__ __forceinline__ short8 mk8(u32 a, u32 b, u32 c, u32 d) {
    u32x4 t; t.x = a; t.y = b; t.z = c; t.w = d;
    return __builtin_bit_cast(short8, t);
}

// ---------------------------------------------------------------------------
// Batched transpose + convert for the four 1024x1024 attention weights:
// z selects {wq,wk,wv,wo}; wq scaled by QK_SCALE (folds softmax scale into Q).
// Block (0,0,z=3) additionally reduces the mask to an "all ones" flag so the
// attention kernel can take a mask-free fast path (wave-uniform branch).
// ---------------------------------------------------------------------------
__global__ __launch_bounds__(256) void transpose_qkvo(
    const float* __restrict__ wq, const float* __restrict__ wk,
    const float* __restrict__ wv, const float* __restrict__ wo,
    u16* __restrict__ qkvT, u16* __restrict__ woT,
    const int* __restrict__ msk, int* __restrict__ flag) {
    __shared__ u16 t[32][33];
    const int z = blockIdx.z;
    const float* W = (z == 0) ? wq : (z == 1) ? wk : (z == 2) ? wv : wo;
    u16* WT = (z < 3) ? (qkvT + (size_t)z * EMB * EMB) : woT;
    const float scale = (z == 0) ? QK_SCALE : 1.0f;
    const int tx = threadIdx.x & 31, ty = threadIdx.x >> 5;
    const int k0 = blockIdx.y * 32, n0 = blockIdx.x * 32;
#pragma unroll
    for (int r = 0; r < 32; r += 8)
        t[ty + r][tx] = f2bf(scale * W[(size_t)(k0 + ty + r) * EMB + n0 + tx]);
    __syncthreads();
#pragma unroll
    for (int r = 0; r < 32; r += 8)
        WT[(size_t)(n0 + ty + r) * EMB + k0 + tx] = t[tx][ty + r];

    if (z == 3 && blockIdx.x == 0 && blockIdx.y == 0) {
        int v = 1;
        for (int i = threadIdx.x; i < BATCH * SEQ; i += 256)
            v &= (msk[i] != 0) ? 1 : 0;
        v = __all(v) ? 1 : 0;
        __shared__ int rr[4];
        if ((threadIdx.x & 63) == 0) rr[threadIdx.x >> 6] = v;
        __syncthreads();
        if (threadIdx.x == 0) flag[0] = rr[0] & rr[1] & rr[2] & rr[3];
    }
}

// ---------------------------------------------------------------------------
// Transpose + convert: W fp32 [K][N] -> WT bf16 [N][K]. 32x32 LDS tiles.
// ---------------------------------------------------------------------------
__global__ __launch_bounds__(256) void transpose_bf16(
    const float* __restrict__ W, u16* __restrict__ WT, int K, int N) {
    __shared__ u16 t[32][33];
    const int tx = threadIdx.x & 31, ty = threadIdx.x >> 5;  // ty 0..7
    const int k0 = blockIdx.y * 32, n0 = blockIdx.x * 32;
#pragma unroll
    for (int r = 0; r < 32; r += 8)
        t[ty + r][tx] = f2bf(W[(size_t)(k0 + ty + r) * N + n0 + tx]);
    __syncthreads();
#pragma unroll
    for (int r = 0; r < 32; r += 8)
        WT[(size_t)(n0 + ty + r) * K + k0 + tx] = t[tx][ty + r];
}

// ---------------------------------------------------------------------------
// LayerNorm: one block per row of 1024, fp32 in, bf16 out. Bessel var,
// denom (std+eps), scalar alpha/beta.
// ---------------------------------------------------------------------------
__global__ __launch_bounds__(256) void ln_kernel(
    const float* __restrict__ x, u16* __restrict__ out,
    const float* __restrict__ alpha_p, const float* __restrict__ beta_p) {
    const int row = blockIdx.x;
    const int tid = threadIdx.x;
    float4 v = reinterpret_cast<const float4*>(x + (size_t)row * EMB)[tid];

    __shared__ float red[4];
    float s = v.x + v.y + v.z + v.w;
    for (int off = 32; off; off >>= 1) s += __shfl_down(s, off);
    if ((tid & 63) == 0) red[tid >> 6] = s;
    __syncthreads();
    float mean = (red[0] + red[1] + red[2] + red[3]) * (1.0f / EMB);
    __syncthreads();

    float d0 = v.x - mean, d1 = v.y - mean, d2 = v.z - mean, d3 = v.w - mean;
    float sq = d0 * d0 + d1 * d1 + d2 * d2 + d3 * d3;
    for (int off = 32; off; off >>= 1) sq += __shfl_down(sq, off);
    if ((tid & 63) == 0) red[tid >> 6] = sq;
    __syncthreads();
    float var = (red[0] + red[1] + red[2] + red[3]) * (1.0f / (EMB - 1));
    float inv = 1.0f / (sqrtf(var) + 1e-6f);
    float a = alpha_p[0], b = beta_p[0];

    ushort4 o;
    o.x = f2bf(a * d0 * inv + b);
    o.y = f2bf(a * d1 * inv + b);
    o.z = f2bf(a * d2 * inv + b);
    o.w = f2bf(a * d3 * inv + b);
    reinterpret_cast<ushort4*>(out + (size_t)row * EMB)[tid] = o;
}

// ---------------------------------------------------------------------------
// MFMA GEMM, 512 threads (8 waves). C[M,N] = A[M,K] @ B[K,N], B transposed
// bf16 (BT [N][K]). 128 x BN tile. LDS rows 128B = 8x16B groups, group g at
// slot g^(row&7) (swizzle folded into the global source address) -> frag
// ds_read_b128 2-way = free.
//
// Pipeline (NBUF):
//  - BN==128: 2-buffer, one __syncthreads()/K-step. 64 KB LDS.
//  - BN==64: 3-buffer, COUNTED vmcnt (2 tiles in flight, never drained).
//    72 KB LDS, 2 blocks/CU.
//
// XCD remap: bid&7 = XCD; requires gridDim.y % 8 == 0 (here ny=32).
// out_mode: 0 bf16 [M][N] | 1 fp32 [M][N] (+res may alias C) |
//           2 bf16 transposed [N][M] | 3 fused QKV (C=Q, Kb_out=K, VT_out=V^T).
// ---------------------------------------------------------------------------
template <int BN, int NWM>
__global__ __launch_bounds__(512) void gemm_mfma(
    const u16* __restrict__ A, const u16* __restrict__ BT, void* C,
    const float* __restrict__ bias, const void* res,
    int M, int N, int K, int relu, int out_mode,
    u16* __restrict__ Kb_out, u16* __restrict__ VT_out) {
    constexpr int NWN = 8 / NWM;
    constexpr int WM = 128 / (16 * NWM);
    constexpr int WN = BN / (16 * NWN);
    constexpr int NBUF = (BN == 64) ? 3 : 2;
    __shared__ u16 As[NBUF][128][GBK];   // NBUF x 16 KB
    __shared__ u16 Bs[NBUF][BN][GBK];    // NBUF x (8|16) KB

    const int tid = threadIdx.x;
    const int wave = tid >> 6, lane = tid & 63;
    const int quad = lane >> 4, lc = lane & 15;
    const int wm = wave % NWM, wn = wave / NWM;

    // XCD-aware remap (speed-only heuristic)
    const int nx = gridDim.x;
    const int bid = blockIdx.y * nx + blockIdx.x;
    const int xcd = bid & 7, sl = bid >> 3;
    const int nyx = gridDim.y >> 3;
    const int bcol = sl % nx;
    const int brow = (sl / nx) + xcd * nyx;
    const int row0 = brow * 128, col0 = bcol * BN;

    // Staging lane map: 8 rows per instr; swizzled global group.
    const int srow = lane >> 3;            // 0..7
    const int scg = (lane & 7) ^ srow;     // global 16B-group for this lane

    f32x4 acc[WM][WN] = {};

    auto stage = [&](int k0, int buf) {
#pragma unroll
        for (int i = 0; i < 2; ++i) {      // A: 128 rows, 8 waves x 2 instrs
            const int rb = wave * 16 + i * 8;
            gl_lds16(A + (size_t)(row0 + rb + srow) * K + k0 + scg * 8,
                     &As[buf][rb][0]);
        }
        if constexpr (BN == 128) {
#pragma unroll
            for (int i = 0; i < 2; ++i) {
                const int rb = wave * 16 + i * 8;
                gl_lds16(BT + (size_t)(col0 + rb + srow) * K + k0 + scg * 8,
                         &Bs[buf][rb][0]);
            }
        } else {                            // BN == 64: 1 instr/wave
            const int rb = wave * 8;
            gl_lds16(BT + (size_t)(col0 + rb + srow) * K + k0 + scg * 8,
                     &Bs[buf][rb][0]);
        }
    };

    auto compute = [&](int cur) {
#pragma unroll
        for (int s = 0; s < 2; ++s) {      // two K=32 substeps per BK=64
            short8 af[WM], bfv[WN];
#pragma unroll
            for (int i = 0; i < WM; ++i) {
                const int ar = wm * (16 * WM) + i * 16 + lc;
                af[i] = *reinterpret_cast<const short8*>(
                    &As[cur][ar][(((s * 4 + quad) ^ (ar & 7))) * 8]);
            }
#pragma unroll
            for (int j = 0; j < WN; ++j) {
                const int br = wn * (16 * WN) + j * 16 + lc;
                bfv[j] = *reinterpret_cast<const short8*>(
                    &Bs[cur][br][(((s * 4 + quad) ^ (br & 7))) * 8]);
            }
#pragma unroll
            for (int i = 0; i < WM; ++i)
#pragma unroll
                for (int j = 0; j < WN; ++j)
                    acc[i][j] = mfma16(af[i], bfv[j], acc[i][j]);
        }
    };

    if constexpr (NBUF == 2) {
        stage(0, 0);
        __syncthreads();                    // drain -> chunk 0 resident
        int cur = 0;
        for (int k0 = 0; k0 < K; k0 += GBK) {
            if (k0 + GBK < K) stage(k0 + GBK, cur ^ 1);  // prefetch, no wait
            compute(cur);
            __syncthreads();   // publishes prefetched chunk; ends reads of cur
            cur ^= 1;
        }
    } else {
        // 3-buffer counted-vmcnt pipeline (2 tiles always in flight).
        stage(0, 0);
        if (GBK < K) stage(GBK, 1);
        int cur = 0;
        for (int k0 = 0; k0 < K; k0 += GBK) {
            if (k0 + 2 * GBK < K) {
                int nb = cur + 2; if (nb >= 3) nb -= 3;
                stage(k0 + 2 * GBK, nb);    // overwrites buffer whose reads
            }                               // ended at last iter's barrier(b)
            const int rem = (K - k0) >> 6;  // tiles remaining incl. current
            if (rem > 2)       asm volatile("s_waitcnt vmcnt(6)" ::: "memory");
            else if (rem == 2) asm volatile("s_waitcnt vmcnt(3)" ::: "memory");
            else               asm volatile("s_waitcnt vmcnt(0)" ::: "memory");
            __builtin_amdgcn_s_barrier();           // (a) tile cur resident
            __builtin_amdgcn_sched_barrier(0);      // rule #18 fence
            compute(cur);
            __builtin_amdgcn_s_barrier();           // (b) reads of cur done
            cur = (cur == 2) ? 0 : cur + 1;
        }
    }

    // Resolve output target (mode 3: segment-uniform per block since BN<=1024).
    u16* Cb = (u16*)C;
    int mode = out_mode, ncols = N, lcol0 = col0;
    if (out_mode == 3) {
        const int seg = col0 >> 10;
        lcol0 = col0 & 1023;
        ncols = EMB;
        if (seg == 1) { Cb = Kb_out; mode = 0; }
        else if (seg == 2) { Cb = VT_out; mode = 2; }
        else { mode = 0; }
    }

    // Epilogue. C/D layout: col = lc, row = quad*4 + r.
#pragma unroll
    for (int j = 0; j < WN; ++j) {
        const int col = lcol0 + wn * (16 * WN) + j * 16 + lc;
        const float bv = bias ? bias[col] : 0.f;
#pragma unroll
        for (int i = 0; i < WM; ++i) {
            const int rbase = row0 + wm * (16 * WM) + i * 16 + quad * 4;
            if (mode == 2) {  // bf16 transposed [N][M]
                ushort4 o;
                o.x = f2bf(acc[i][j][0]); o.y = f2bf(acc[i][j][1]);
                o.z = f2bf(acc[i][j][2]); o.w = f2bf(acc[i][j][3]);
                *reinterpret_cast<ushort4*>(Cb + (size_t)col * M + rbase) = o;
            } else {
#pragma unroll
                for (int r = 0; r < 4; ++r) {
                    const size_t idx = (size_t)(rbase + r) * ncols + col;
                    float v = acc[i][j][r] + bv;
                    if (relu) v = fmaxf(v, 0.f);
                    if (res) v += ((const float*)res)[idx];
                    if (mode == 1) ((float*)C)[idx] = v;
                    else Cb[idx] = f2bf(v);
                }
            }
        }
    }
}

// ---------------------------------------------------------------------------
// FFN GEMM v3 "wide-tile + K-stream split": 512 threads = 8 waves =
// 4 output positions (64x64 each, 2x2 over the 128x128 block tile) x
// 2 K-STREAMS. Stream s computes only substep s of every shared BK=64 tile.
// Per wave per K-step: 8 zero-conflict ds_read_b128 + 16 mfma16.
// 2-buffer + counted vmcnt(4). End: stream pairs merge acc via LDS, then a
// conflict-free, fully-coalesced flat epilogue. 64 KB LDS.
// ---------------------------------------------------------------------------
__global__ __launch_bounds__(512) void gemm_ws(
    const u16* __restrict__ A, const u16* __restrict__ BT, void* C,
    const float* __restrict__ bias, const void* res,
    int M, int N, int K, int relu, int fp32out) {
    __shared__ __align__(16) char smem[65536];
    u16 (*As)[128][GBK] = (u16(*)[128][GBK])smem;            // [2][128][64] 32 KB
    u16 (*Bs)[128][GBK] = (u16(*)[128][GBK])(smem + 32768);  // [2][128][64] 32 KB

    const int tid = threadIdx.x;
    const int wave = tid >> 6, lane = tid & 63;
    const int quad = lane >> 4, lc = lane & 15;
    const int p = wave >> 1, s = wave & 1;     // position, K-stream
    const int pm = p >> 1, pn = p & 1;         // 2x2 position grid

    // XCD-aware remap
    const int nx = gridDim.x;
    const int bid = blockIdx.y * nx + blockIdx.x;
    const int xcd = bid & 7, sl = bid >> 3;
    const int nyx = gridDim.y >> 3;
    const int bcol = sl % nx;
    const int brow = (sl / nx) + xcd * nyx;
    const int row0 = brow * 128, col0 = bcol * 128;

    // Staging lane map: 8 rows/instr; swizzled global 16B-group.
    const int srow = lane >> 3;
    const int scg = (lane & 7) ^ srow;

    f32x4 acc[4][4] = {};

    auto stage = [&](int k0, int buf) {
#pragma unroll
        for (int i = 0; i < 2; ++i) {          // A: 128 rows, 8 waves x 2
            const int rb = wave * 16 + i * 8;
            gl_lds16(A + (size_t)(row0 + rb + srow) * K + k0 + scg * 8,
                     &As[buf][rb][0]);
        }
#pragma unroll
        for (int i = 0; i < 2; ++i) {          // B: 128 cols (BT rows)
            const int rb = wave * 16 + i * 8;
            gl_lds16(BT + (size_t)(col0 + rb + srow) * K + k0 + scg * 8,
                     &Bs[buf][rb][0]);
        }
    };

    const int nt = K >> 6;
    stage(0, 0);
    int cur = 0;
    for (int t = 0; t < nt; ++t) {
        if (t + 1 < nt) {
            stage((t + 1) << 6, cur ^ 1);      // prefetch next tile
            asm volatile("s_waitcnt vmcnt(4)" ::: "memory");  // tile t landed
        } else {
            asm volatile("s_waitcnt vmcnt(0)" ::: "memory");
        }
        __builtin_amdgcn_s_barrier();           // (a) tile t resident
        __builtin_amdgcn_sched_barrier(0);      // rule #18 fence

        // This wave's substep only: k-groups s*4+quad (k = s*32..s*32+31).
        short8 af[4], bfv[4];
#pragma unroll
        for (int i = 0; i < 4; ++i) {
            const int ar = pm * 64 + i * 16 + lc;
            af[i] = *reinterpret_cast<const short8*>(
                &As[cur][ar][(((s * 4 + quad) ^ (ar & 7))) * 8]);
        }
#pragma unroll
        for (int j = 0; j < 4; ++j) {
            const int br = pn * 64 + j * 16 + lc;
            bfv[j] = *reinterpret_cast<const short8*>(
                &Bs[cur][br][(((s * 4 + quad) ^ (br & 7))) * 8]);
        }
#pragma unroll
        for (int i = 0; i < 4; ++i)
#pragma unroll
            for (int j = 0; j < 4; ++j)
                acc[i][j] = mfma16(af[i], bfv[j], acc[i][j]);

        __builtin_amdgcn_s_barrier();           // (b) reads of cur done
        cur ^= 1;
    }

    // ---- K-stream merge via LDS (overwrites staging; loop's trailing
    // barrier guarantees all As/Bs reads completed). C/D: row=quad*4+r, col=lc.
    float* Ms = (float*)smem;                   // [128][128] fp32 = 64 KB
    if (s == 0) {
#pragma unroll
        for (int i = 0; i < 4; ++i)
#pragma unroll
            for (int j = 0; j < 4; ++j)
#pragma unroll
                for (int r = 0; r < 4; ++r)
                    Ms[(pm * 64 + i * 16 + quad * 4 + r) * 128 +
                       pn * 64 + j * 16 + lc] = acc[i][j][r];
    }
    __syncthreads();
    if (s == 1) {
#pragma unroll
        for (int i = 0; i < 4; ++i)
#pragma unroll
            for (int j = 0; j < 4; ++j)
#pragma unroll
                for (int r = 0; r < 4; ++r)
                    Ms[(pm * 64 + i * 16 + quad * 4 + r) * 128 +
                       pn * 64 + j * 16 + lc] += acc[i][j][r];
    }
    __syncthreads();

    // ---- flat coalesced epilogue: lane-contiguous float4 LDS reads
    // (conflict-free), consecutive tids -> consecutive global 16B. ----
#pragma unroll
    for (int k = 0; k < 8; ++k) {
        const int fi = (k * 512 + tid) * 4;     // float index in [0,16384)
        const int row = fi >> 7, col = fi & 127;
        const float4 v = *reinterpret_cast<const float4*>(&Ms[fi]);
        float o0 = v.x, o1 = v.y, o2 = v.z, o3 = v.w;
        if (bias) {
            const float4 bv = *reinterpret_cast<const float4*>(&bias[col0 + col]);
            o0 += bv.x; o1 += bv.y; o2 += bv.z; o3 += bv.w;
        }
        if (relu) {
            o0 = fmaxf(o0, 0.f); o1 = fmaxf(o1, 0.f);
            o2 = fmaxf(o2, 0.f); o3 = fmaxf(o3, 0.f);
        }
        const size_t gidx = (size_t)(row0 + row) * N + col0 + col;
        if (res) {
            const float4 rv = *reinterpret_cast<const float4*>(
                &((const float*)res)[gidx]);
            o0 += rv.x; o1 += rv.y; o2 += rv.z; o3 += rv.w;
        }
        if (fp32out) {
            float4 ov; ov.x = o0; ov.y = o1; ov.z = o2; ov.w = o3;
            *reinterpret_cast<float4*>(&((float*)C)[gidx]) = ov;
        } else {
            ushort4 ov;
            ov.x = f2bf(o0); ov.y = f2bf(o1); ov.z = f2bf(o2); ov.w = f2bf(o3);
            *reinterpret_cast<ushort4*>(&((u16*)C)[gidx]) = ov;
        }
    }
}

// ---------------------------------------------------------------------------
// MFMA flash attention v5: 32x32x16 MFMA, 512 threads = 8 waves =
// 4 query-PAIRS (64 q each: two 32-query tiles) x 2 key-streams. Block
// covers 256 queries of one (b,h); grid 256 blocks (8 qblk x 32 heads),
// 1 block/CU, XCD affinity preserved (bid&7 head-invariant).
// KEY CHANGE vs v4 (round-8 PMC: MfmaUtil 24%, LDS:MFMA = 5:1): each wave
// owns TWO query tiles, so every Ks fragment feeds 2 QK mfma32 and every
// Vs fragment feeds 2 PV mfma32 -> LDS bytes per FLOP HALVED (ratio 2.5:1,
// MfmaUtil cap ~40%). Also: counted-vmcnt(4) barriers (gemm_ws's proven
// pattern) replace the per-chunk __syncthreads vmcnt(0) drain, and the two
// independent st/o chains double intra-wave ILP.
// Same verified primitives: staging maps, QK/PV fragment math, v_perm pack,
// permlane32_swap, 2-stream O/denominator merge via LDS.
// ---------------------------------------------------------------------------
__global__ __launch_bounds__(512, 2) void attn_mfma(
    const u16* __restrict__ Q, const u16* __restrict__ K,
    const u16* __restrict__ VT, const int* __restrict__ mask,
    const int* __restrict__ mflag, u16* __restrict__ O) {
    const int tid = threadIdx.x;
    const int wave = tid >> 6, lane = tid & 63;
    const int hi = lane >> 5, ln31 = lane & 31;
    const int qp = wave >> 1, s = wave & 1;   // query-pair, key-stream
    const int H = blockIdx.x & 31;            // b*16+h
    const int qblk = blockIdx.x >> 5;         // 0..7 (256 queries each)
    const int h = H & 15, b = H >> 4;

    // LDS arena: main loop Ks+Vs (64 KB); epilogue Om[8][32][68] + Ls[256].
    __shared__ __align__(16) char smem[70656];
    u16 (*Ks)[128][DKH] = (u16(*)[128][DKH])smem;            // [2][128][64]
    u16 (*Vs)[DKH][128] = (u16(*)[DKH][128])(smem + 32768);  // [2][64][128]

    const int fast = mflag[0];

    // Q as B-operand frags for BOTH tiles: B[k = f*16 + hi*8 + j][n = q = ln31]
    short8 qb[2][4];
#pragma unroll
    for (int t = 0; t < 2; ++t) {
        const u16* qsrc = Q + (size_t)(b * SEQ + qblk * 256 + qp * 64 + t * 32 + ln31) * EMB
                            + h * DKH + hi * 8;
#pragma unroll
        for (int f = 0; f < 4; ++f)
            qb[t][f] = *reinterpret_cast<const short8*>(qsrc + f * 16);
    }

    // Staging lane maps (swizzle folded into GLOBAL source; LDS dest linear).
    const int srow = lane >> 3, scg = (lane & 7) ^ srow;   // K: 8 tok/instr
    const int svr = lane >> 4, ssl = lane & 15;            // V: 4 dim/instr

    auto stage = [&](int kc, int buf) {
#pragma unroll
        for (int i = 0; i < 2; ++i) {      // K: 128 tokens, 8 waves x 2
            const int t8 = wave * 16 + i * 8;
            gl_lds16(K + (size_t)(b * SEQ + kc + t8 + srow) * EMB + h * DKH + scg * 8,
                     &Ks[buf][t8][0]);
        }
#pragma unroll
        for (int i = 0; i < 2; ++i) {      // V^T: 64 dims, 8 waves x 2
            const int d4 = wave * 8 + i * 4;
            const int dim = d4 + svr;
            const int gv = ssl ^ (dim & 15);
            gl_lds16(VT + (size_t)(h * DKH + dim) * MROWS + b * SEQ + kc + gv * 8,
                     &Vs[buf][d4][0]);
        }
    };

    f32x16 o00 = {}, o01 = {}, o10 = {}, o11 = {};  // o[t][nt]
    float rs0 = 0.f, rs1 = 0.f;
    const int tok0 = s * 64;   // this wave's key base within the 128-chunk

    const int NCH = SEQ / 128;             // 16 chunks
    stage(0, 0);
    int cur = 0;

    for (int tch = 0; tch < NCH; ++tch) {
        if (tch + 1 < NCH) {
            stage((tch + 1) * 128, cur ^ 1);   // prefetch next chunk
            asm volatile("s_waitcnt vmcnt(4)" ::: "memory");  // chunk tch landed
        } else {
            asm volatile("s_waitcnt vmcnt(0)" ::: "memory");
        }
        __builtin_amdgcn_s_barrier();           // (a) chunk resident
        __builtin_amdgcn_sched_barrier(0);      // rule #18 fence
        const int kc = tch * 128;

#pragma unroll
        for (int mt = 0; mt < 2; ++mt) {   // two 32-key m-tiles per stream
            const int trow = tok0 + mt * 32 + ln31;
            f32x16 st0 = {}, st1 = {};
#pragma unroll
            for (int f = 0; f < 4; ++f) {  // K-dim 64 = 4 steps of 16
                const int slot = (2 * f + hi) ^ (trow & 7);
                const short8 ka = *reinterpret_cast<const short8*>(
                    &Ks[cur][trow][slot * 8]);
                st0 = mfma32(ka, qb[0][f], st0);    // Ks frag reused 2x
                st1 = mfma32(ka, qb[1][f], st1);
            }
            // st*[r]: score(key = mt*32 + (r&3)+8*(r>>2)+4*hi, query = ln31)
            int4 mks[4];
            if (!fast) {
#pragma unroll
                for (int g = 0; g < 4; ++g)
                    mks[g] = *reinterpret_cast<const int4*>(
                        mask + b * SEQ + kc + tok0 + mt * 32 + g * 8 + hi * 4);
            }
            short8 fr[2][2];
#pragma unroll
            for (int t = 0; t < 2; ++t) {
                f32x16& st = t ? st1 : st0;
                if (fast) {
#pragma unroll
                    for (int r = 0; r < 16; ++r)
                        st[r] = pexp(fminf(st[r], QK_CLAMP));
                } else {
#pragma unroll
                    for (int g = 0; g < 4; ++g) {
                        const int* mkp = &mks[g].x;
#pragma unroll
                        for (int r4 = 0; r4 < 4; ++r4) {
                            const int r = g * 4 + r4;
                            const float pv = pexp(fminf(st[r], QK_CLAMP));
                            st[r] = mkp[r4] ? pv : 0.f;
                        }
                    }
                }
                const float sum =
                    (((st[0] + st[1]) + (st[2] + st[3])) +
                     ((st[4] + st[5]) + (st[6] + st[7]))) +
                    (((st[8] + st[9]) + (st[10] + st[11])) +
                     ((st[12] + st[13]) + (st[14] + st[15])));
                if (t) rs1 += sum; else rs0 += sum;

                // Truncating bf16 pack + lane<->lane+32 swaps -> PV A-frags.
                u32 pk0 = __builtin_amdgcn_perm(__float_as_uint(st[1]),
                                                __float_as_uint(st[0]), 0x07060302u);
                u32 pk1 = __builtin_amdgcn_perm(__float_as_uint(st[3]),
                                                __float_as_uint(st[2]), 0x07060302u);
                u32 pk2 = __builtin_amdgcn_perm(__float_as_uint(st[5]),
                                                __float_as_uint(st[4]), 0x07060302u);
                u32 pk3 = __builtin_amdgcn_perm(__float_as_uint(st[7]),
                                                __float_as_uint(st[6]), 0x07060302u);
                u32 pk4 = __builtin_amdgcn_perm(__float_as_uint(st[9]),
                                                __float_as_uint(st[8]), 0x07060302u);
                u32 pk5 = __builtin_amdgcn_perm(__float_as_uint(st[11]),
                                                __float_as_uint(st[10]), 0x07060302u);
                u32 pk6 = __builtin_amdgcn_perm(__float_as_uint(st[13]),
                                                __float_as_uint(st[12]), 0x07060302u);
                u32 pk7 = __builtin_amdgcn_perm(__float_as_uint(st[15]),
                                                __float_as_uint(st[14]), 0x07060302u);
                plswap(pk0, pk2);
                plswap(pk1, pk3);
                plswap(pk4, pk6);
                plswap(pk5, pk7);
                fr[t][0] = mk8(pk0, pk1, pk2, pk3);  // keys mt*32 +  0..15
                fr[t][1] = mk8(pk4, pk5, pk6, pk7);  // keys mt*32 + 16..31
            }

#pragma unroll
            for (int sub = 0; sub < 2; ++sub) {
                const int g = s * 8 + (2 * mt + sub) * 2 + hi;  // token 16B-group
#pragma unroll
                for (int nt = 0; nt < 2; ++nt) {
                    const int drow = nt * 32 + ln31;
                    const short8 vb = *reinterpret_cast<const short8*>(
                        &Vs[cur][drow][(g ^ (drow & 15)) * 8]);
                    if (nt == 0) {                     // Vs frag reused 2x
                        o00 = mfma32(fr[0][sub], vb, o00);
                        o10 = mfma32(fr[1][sub], vb, o10);
                    } else {
                        o01 = mfma32(fr[0][sub], vb, o01);
                        o11 = mfma32(fr[1][sub], vb, o11);
                    }
                }
            }
        }
        __builtin_amdgcn_s_barrier();           // (b) reads of cur done
        cur ^= 1;
    }

    // ---- merge the two key-streams of each query-pair via LDS ----
    rs0 += __shfl_xor(rs0, 32);            // full stream-partials per query
    rs1 += __shfl_xor(rs1, 32);

    float* Om = (float*)smem;              // [8][32][68] fp32 (padded rows)
    float* Ls = (float*)(smem + 69632);    // [256]

    if (s == 0) {
#pragma unroll
        for (int t = 0; t < 2; ++t) {
            const int tile = qp * 2 + t;
#pragma unroll
            for (int nt = 0; nt < 2; ++nt) {
                const f32x16& ov = t ? (nt ? o11 : o10) : (nt ? o01 : o00);
#pragma unroll
                for (int r = 0; r < 16; ++r) {
                    const int row = (r & 3) + 8 * (r >> 2) + 4 * hi;
                    Om[(tile * 32 + row) * 68 + nt * 32 + ln31] = ov[r];
                }
            }
            if (lane < 32) Ls[tile * 32 + ln31] = t ? rs1 : rs0;
        }
    }
    __syncthreads();
    if (s == 1) {
#pragma unroll
        for (int t = 0; t < 2; ++t) {
            const int tile = qp * 2 + t;
            if (lane < 32) Ls[tile * 32 + ln31] += (t ? rs1 : rs0);
#pragma unroll
            for (int nt = 0; nt < 2; ++nt) {
                const f32x16& ov = t ? (nt ? o11 : o10) : (nt ? o01 : o00);
#pragma unroll
                for (int r = 0; r < 16; ++r) {
                    const int row = (r & 3) + 8 * (r >> 2) + 4 * hi;
                    Om[(tile * 32 + row) * 68 + nt * 32 + ln31] += ov[r];
                }
            }
        }
    }
    __syncthreads();

    // ---- coalesced vectorized writeback: thread -> (q = tid>>1, seg) ----
    {
        const int q = tid >> 1, seg = tid & 1;     // 256 q x 2 half-rows
        const float inv = 1.0f / Ls[q];
        const float* src = Om + q * 68 + seg * 32;
        u16* dst = O + (size_t)(b * SEQ + qblk * 256 + q) * EMB + h * DKH + seg * 32;
#pragma unroll
        for (int i = 0; i < 8; ++i) {
            const float4 v = *reinterpret_cast<const float4*>(src + i * 4);
            ushort4 ou;
            ou.x = f2bf(v.x * inv); ou.y = f2bf(v.y * inv);
            ou.z = f2bf(v.z * inv); ou.w = f2bf(v.w * inv);
            *reinterpret_cast<ushort4*>(dst + i * 4) = ou;
        }
    }
}

// ---------------------------------------------------------------------------
// Orchestration. fp32 I/O, bf16 internals. ws (48 MB):
//   [0,8M)    act: xn -> attn_out -> xn2
//   [8,16M)   Q   --+
//   [16,24M)  K     +-- overlaid by f1 [8,40M) after attention
//   [24,32M)  VT  --+
//   [32M)     mask all-ones flag (int; dead once f1 is written)
//   [40,46M)  wqkvT [3072][1024]; [46,48M) woT --> later ffT [40,48M)
// h (fp32) lives in d_out (in-place residual in final GEMM).
// ---------------------------------------------------------------------------
extern "C" void kernel_launch(void* const* d_in, const int* in_sizes, int n_in,
                              void* d_out, int out_size, void* d_ws, size_t ws_size,
                              hipStream_t stream) {
    const float* x     = (const float*)d_in[0];
    const int*   mask  = (const int*)d_in[1];
    const float* wq    = (const float*)d_in[2];
    const float* wk    = (const float*)d_in[3];
    const float* wv    = (const float*)d_in[4];
    const float* wo    = (const float*)d_in[5];
    const float* ff1_w = (const float*)d_in[6];
    const float* ff1_b = (const float*)d_in[7];
    const float* ff2_w = (const float*)d_in[8];
    const float* ff2_b = (const float*)d_in[9];
    const float* ln1_a = (const float*)d_in[10];
    const float* ln1_b = (const float*)d_in[11];
    const float* ln2_a = (const float*)d_in[12];
    const float* ln2_b = (const float*)d_in[13];
    float* out = (float*)d_out;

    char* ws = (char*)d_ws;
    const size_t MB = 1u << 20;
    u16* act   = (u16*)(ws + 0);
    u16* Qb    = (u16*)(ws + 8 * MB);
    u16* Kb    = (u16*)(ws + 16 * MB);
    u16* VTb   = (u16*)(ws + 24 * MB);
    int* mflag = (int*)(ws + 32 * MB);   // free until f1 is written (step 6)
    u16* f1    = (u16*)(ws + 8 * MB);    // 32 MB, overlays Q/K/VT (dead)
    u16* wqkvT = (u16*)(ws + 40 * MB);   // [3*EMB][EMB] bf16 = 6 MB
    u16* woT   = (u16*)(ws + 46 * MB);   // 2 MB
    u16* ffT   = (u16*)(ws + 40 * MB);   // 8 MB rotating (ff1T, then ff2T)

    // 0) batched weight transposes (wq scaled by QK_SCALE inside the kernel)
    //    + mask all-ones flag reduction (block (0,0,3))
    transpose_qkvo<<<dim3(EMB / 32, EMB / 32, 4), 256, 0, stream>>>(
        wq, wk, wv, wo, wqkvT, woT, mask, mflag);

    // 1) LN1: x -> act
    ln_kernel<<<MROWS, 256, 0, stream>>>(x, act, ln1_a, ln1_b);

    // 2) fused QKV: [4096,3072] -> Qb, Kb (natural), VTb (transposed)
    gemm_mfma<128, 2><<<dim3(3 * EMB / 128, MROWS / 128), 512, 0, stream>>>(
        act, wqkvT, Qb, nullptr, nullptr, MROWS, 3 * EMB, EMB, 0, 3, Kb, VTb);

    // 3) attention -> act (v5: 256 q/block, 2 query-tiles/wave K/V reuse)
    attn_mfma<<<BATCH * NHEADS * (SEQ / 256), 512, 0, stream>>>(
        Qb, Kb, VTb, mask, mflag, act);

    // 4) h = attn @ wo + x -> d_out (fp32), BN=64 3-buffer counted-vmcnt
    gemm_mfma<64, 4><<<dim3(EMB / 64, MROWS / 128), 512, 0, stream>>>(
        act, woT, out, nullptr, x, MROWS, EMB, EMB, 0, 1, nullptr, nullptr);

    // 5) LN2: h -> act
    ln_kernel<<<MROWS, 256, 0, stream>>>(out, act, ln2_a, ln2_b);

    // 6) FF1: f1 = relu(act @ ff1 + b1) (bf16), K-stream-split wide GEMM
    transpose_bf16<<<dim3(HID / 32, EMB / 32), 256, 0, stream>>>(ff1_w, ffT, EMB, HID);
    gemm_ws<<<dim3(HID / 128, MROWS / 128), 512, 0, stream>>>(
        act, ffT, f1, ff1_b, nullptr, MROWS, HID, EMB, 1, 0);

    // 7) FF2: out = f1 @ ff2 + b2 + h (in-place fp32 residual), same GEMM
    transpose_bf16<<<dim3(EMB / 32, HID / 32), 256, 0, stream>>>(ff2_w, ffT, HID, EMB);
    gemm_ws<<<dim3(EMB / 128, MROWS / 128), 512, 0, stream>>>(
        f1, ffT, out, ff2_b, out, MROWS, EMB, HID, 0, 1);
}